// Round 3
// baseline (347.321 us; speedup 1.0000x reference)
//
#include <hip/hip_runtime.h>
#include <hip/hip_bf16.h>

#define B_  2
#define S_  2048
#define M_  64
#define D_  1024
#define T_  2112      // M_ + S_
#define H_  16
#define HD_ 64
#define BT_ (B_*T_)   // 4224
#define NEGBIG (-1e9f)
#define LOG2E 1.44269504f

typedef float f32x4  __attribute__((ext_vector_type(4)));
typedef short short8 __attribute__((ext_vector_type(8)));
typedef __bf16 bf16x8 __attribute__((ext_vector_type(8)));

static __device__ __forceinline__ unsigned short bf16_of(float f) {
  __hip_bfloat16 h = __float2bfloat16(f);
  return __builtin_bit_cast(unsigned short, h);
}

static __device__ __forceinline__ f32x4 mfma_bf16(short8 a, short8 b, f32x4 c) {
  return __builtin_amdgcn_mfma_f32_16x16x32_bf16(
      __builtin_bit_cast(bf16x8, a), __builtin_bit_cast(bf16x8, b), c, 0, 0, 0);
}

// async global->LDS, 16B per lane; lds base must be wave-uniform.
static __device__ __forceinline__ void gload16(const void* g, void* lds) {
  __builtin_amdgcn_global_load_lds(
      (const __attribute__((address_space(1))) unsigned int*)g,
      (__attribute__((address_space(3))) unsigned int*)lds, 16, 0, 0);
}

// ---------------- cast / concat kernels ----------------

__global__ void k_build_x(const float* __restrict__ tokens,
                          const float* __restrict__ memory,
                          unsigned short* __restrict__ xb) {
  for (int i = blockIdx.x * blockDim.x + threadIdx.x; i < BT_ * D_;
       i += gridDim.x * blockDim.x) {
    int b = i / (T_ * D_);
    int rem = i - b * (T_ * D_);
    int t = rem / D_;
    int d = rem - t * D_;
    float v = (t < M_) ? memory[((size_t)b * M_ + t) * D_ + d]
                       : tokens[((size_t)b * S_ + (t - M_)) * D_ + d];
    xb[i] = bf16_of(v);
  }
}

// one launch casts: Wq,Wk,Wv,Wo (4 x 1M), cell_W (4M), pool_q (64K, scaled)
__global__ void k_cast_all(const float* __restrict__ Wq, const float* __restrict__ Wk,
                           const float* __restrict__ Wv, const float* __restrict__ Wo,
                           const float* __restrict__ cW, const float* __restrict__ pq,
                           unsigned short* __restrict__ Wqb, unsigned short* __restrict__ Wkb,
                           unsigned short* __restrict__ Wvb, unsigned short* __restrict__ Wob,
                           unsigned short* __restrict__ cWb, unsigned short* __restrict__ pqb) {
  const int NW = D_ * D_;            // 1M
  const int NC = 4 * D_ * D_;        // 4M
  const int NP = M_ * D_;            // 64K
  const int total = 4 * NW + NC + NP;
  for (int i = blockIdx.x * blockDim.x + threadIdx.x; i < total;
       i += gridDim.x * blockDim.x) {
    if (i < 4 * NW) {
      int which = i >> 20, j = i & (NW - 1);
      const float* s = (which == 0) ? Wq : (which == 1) ? Wk : (which == 2) ? Wv : Wo;
      unsigned short* d = (which == 0) ? Wqb : (which == 1) ? Wkb : (which == 2) ? Wvb : Wob;
      d[j] = bf16_of(s[j]);
    } else if (i < 4 * NW + NC) {
      int j = i - 4 * NW;
      cWb[j] = bf16_of(cW[j]);
    } else {
      int j = i - 4 * NW - NC;
      pqb[j] = bf16_of(pq[j] * 0.03125f * LOG2E);   // D^-0.5, exp2-domain
    }
  }
}

// ---------------- 128x128 GEMM core (m97 structure) ----------------
__device__ __forceinline__ void gemm128_core(const unsigned short* __restrict__ A,
                                             const unsigned short* __restrict__ BT,
                                             int K, int m0, int n0,
                                             f32x4 acc[4][4]) {
  __shared__ __align__(16) unsigned short As[128][32];
  __shared__ __align__(16) unsigned short Bs[128][32];
  const int tid = threadIdx.x;
  const int w = tid >> 6, l = tid & 63;
  const int wr = w >> 1, wc = w & 1;
  const int srow = l >> 2;
  const int scol = (l & 3) * 8;
  f32x4 z; z[0] = z[1] = z[2] = z[3] = 0.f;
#pragma unroll
  for (int i = 0; i < 4; i++)
#pragma unroll
    for (int j = 0; j < 4; j++) acc[i][j] = z;

  for (int k0 = 0; k0 < K; k0 += 32) {
    __syncthreads();
#pragma unroll
    for (int c = 0; c < 2; c++) {
      int rbase = w * 32 + c * 16;
      gload16(&A[(size_t)(m0 + rbase + srow) * K + k0 + scol], &As[rbase][0]);
      gload16(&BT[(size_t)(n0 + rbase + srow) * K + k0 + scol], &Bs[rbase][0]);
    }
    __syncthreads();
    short8 a[4], b[4];
#pragma unroll
    for (int i = 0; i < 4; i++)
      a[i] = *(const short8*)&As[wr * 64 + i * 16 + (l & 15)][(l >> 4) * 8];
#pragma unroll
    for (int j = 0; j < 4; j++)
      b[j] = *(const short8*)&Bs[wc * 64 + j * 16 + (l & 15)][(l >> 4) * 8];
#pragma unroll
    for (int i = 0; i < 4; i++)
#pragma unroll
      for (int j = 0; j < 4; j++)
        acc[i][j] = mfma_bf16(a[i], b[j], acc[i][j]);
  }
}

// ---------------- small 64x64 GEMM core (partial-K capable) ----------------
// C[m][n] (64x64) = sum_{k<Klen} A[m][k]*BT[n][k]; rows stride ldk.
__device__ __forceinline__ void gemm_core(const unsigned short* __restrict__ A,
                                          const unsigned short* __restrict__ BT,
                                          int ldk, int Klen, int m0, int n0,
                                          f32x4 acc[4]) {
  __shared__ __align__(16) unsigned short As[64][40];
  __shared__ __align__(16) unsigned short Bs[64][40];
  const int tid = threadIdx.x;
  const int w = tid >> 6, l = tid & 63;
  const int sr = tid >> 2, sc = (tid & 3) * 8;
  f32x4 z; z[0] = z[1] = z[2] = z[3] = 0.f;
  acc[0] = acc[1] = acc[2] = acc[3] = z;
  for (int k0 = 0; k0 < Klen; k0 += 32) {
    __syncthreads();
    *(short8*)&As[sr][sc] = *(const short8*)&A[(size_t)(m0 + sr) * ldk + k0 + sc];
    *(short8*)&Bs[sr][sc] = *(const short8*)&BT[(size_t)(n0 + sr) * ldk + k0 + sc];
    __syncthreads();
    short8 a = *(const short8*)&As[w * 16 + (l & 15)][(l >> 4) * 8];
#pragma unroll
    for (int n = 0; n < 4; n++) {
      short8 b = *(const short8*)&Bs[n * 16 + (l & 15)][(l >> 4) * 8];
      acc[n] = mfma_bf16(a, b, acc[n]);
    }
  }
}

// ---------------- QKV projection (128-tile) ----------------
// grid: x = n-tile (8), y = m-tile (33), z = which (0=q,1=k,2=v)
__global__ __launch_bounds__(256) void k_qkv(
    const unsigned short* __restrict__ xb, const unsigned short* __restrict__ Wqb,
    const unsigned short* __restrict__ Wkb, const unsigned short* __restrict__ Wvb,
    const float* __restrict__ bq, const float* __restrict__ bk,
    const float* __restrict__ bv, unsigned short* __restrict__ qg,
    unsigned short* __restrict__ kg, unsigned short* __restrict__ vTg) {
  const int z = blockIdx.z;
  const unsigned short* W = (z == 0) ? Wqb : ((z == 1) ? Wkb : Wvb);
  const float* bias = (z == 0) ? bq : ((z == 1) ? bk : bv);
  f32x4 acc[4][4];
  const int m0 = blockIdx.y * 128, n0 = blockIdx.x * 128;
  gemm128_core(xb, W, D_, m0, n0, acc);
  const int tid = threadIdx.x, w = tid >> 6, l = tid & 63;
  const int wr = w >> 1, wc = w & 1;
#pragma unroll
  for (int i = 0; i < 4; i++) {
#pragma unroll
    for (int j = 0; j < 4; j++) {
#pragma unroll
      for (int r = 0; r < 4; r++) {
        int m = m0 + wr * 64 + i * 16 + (l >> 4) * 4 + r;
        int c = n0 + wc * 64 + j * 16 + (l & 15);
        int b = m / T_, t = m - b * T_;
        int h = c >> 6, dh = c & 63;
        int bh = b * H_ + h;
        float v = acc[i][j][r] + bias[c];
        if (z == 0)
          qg[((size_t)bh * T_ + t) * HD_ + dh] = bf16_of(v * 0.125f * LOG2E);
        else if (z == 1)
          kg[((size_t)bh * T_ + t) * HD_ + dh] = bf16_of(v);
        else
          vTg[((size_t)bh * HD_ + dh) * T_ + t] = bf16_of(v);
      }
    }
  }
}

// ---------------- fused attention: barrier-free, direct-L2 K/V ----------------
// grid: 544 blocks 1D.  id = 8*((bh/8)*17 + (16-qi)) + bh%8  (bh-groups pinned
// to XCDs assuming round-robin id%8 dispatch; heavy q-tiles first).
// Block = 4 waves; wave w owns 32 q-rows [qi*128 + w*32, +32)  (2 sub-tiles of 16).
__global__ __launch_bounds__(256) void k_attn(
    const unsigned short* __restrict__ qg, const unsigned short* __restrict__ kg,
    const unsigned short* __restrict__ vTg, unsigned short* __restrict__ ctx) {
  const int id = blockIdx.x;
  const int xcd = id & 7;
  const int rem = id >> 3;
  const int g = rem / 17, qir = rem - g * 17;
  const int qi = 16 - qir;
  const int bh = g * 8 + xcd;
  const int tid = threadIdx.x, w = tid >> 6, l = tid & 63;
  const int lr = l & 15, lg = l >> 4;
  __shared__ __align__(16) unsigned short Ps[4][32][72];

  const unsigned short* qb = qg + (size_t)bh * T_ * HD_;
  const unsigned short* kb = kg + (size_t)bh * T_ * HD_;
  const unsigned short* vb = vTg + (size_t)bh * HD_ * T_;

  // q fragments: 2 sub-tiles x 2 k-steps
  short8 aq[2][2];
#pragma unroll
  for (int mi = 0; mi < 2; mi++) {
    int tq = qi * 128 + w * 32 + mi * 16 + lr;
    int tqc = tq < T_ ? tq : T_ - 1;
#pragma unroll
    for (int st = 0; st < 2; st++)
      aq[mi][st] = *(const short8*)&qb[(size_t)tqc * HD_ + st * 32 + lg * 8];
  }

  f32x4 zz; zz[0] = zz[1] = zz[2] = zz[3] = 0.f;
  f32x4 o[2][4];
  float mrun[2][4], lrun[2][4];
#pragma unroll
  for (int mi = 0; mi < 2; mi++)
#pragma unroll
    for (int n = 0; n < 4; n++) o[mi][n] = zz;
#pragma unroll
  for (int mi = 0; mi < 2; mi++)
#pragma unroll
    for (int r = 0; r < 4; r++) { mrun[mi][r] = -1e30f; lrun[mi][r] = 0.f; }

  const int nkt = (qi == 0) ? 33 : ((2 * qi + 2 < 33) ? 2 * qi + 2 : 33);
  const int qmin = (qi == 0) ? M_ : qi * 128;

  for (int j = 0; j < nkt; j++) {
    const int kbase = j * 64;
    // K fragments straight from L2
    short8 bk[2][4];
#pragma unroll
    for (int n = 0; n < 4; n++) {
      int t = kbase + n * 16 + lr;
#pragma unroll
      for (int st = 0; st < 2; st++)
        bk[st][n] = *(const short8*)&kb[(size_t)t * HD_ + st * 32 + lg * 8];
    }
    f32x4 s[2][4];
#pragma unroll
    for (int mi = 0; mi < 2; mi++)
#pragma unroll
      for (int n = 0; n < 4; n++) s[mi][n] = zz;
#pragma unroll
    for (int st = 0; st < 2; st++)
#pragma unroll
      for (int mi = 0; mi < 2; mi++)
#pragma unroll
        for (int n = 0; n < 4; n++)
          s[mi][n] = mfma_bf16(aq[mi][st], bk[st][n], s[mi][n]);

    // causal mask (memory rows tq<M_ attend everywhere)
    if (kbase + 63 > qmin) {
#pragma unroll
      for (int mi = 0; mi < 2; mi++)
#pragma unroll
        for (int n = 0; n < 4; n++)
#pragma unroll
          for (int r = 0; r < 4; r++) {
            int tq = qi * 128 + w * 32 + mi * 16 + lg * 4 + r;
            int tk = kbase + n * 16 + lr;
            if (tq >= M_ && tk > tq) s[mi][n][r] = NEGBIG;
          }
    }
    // online softmax in exp2 domain (scale pre-folded)
#pragma unroll
    for (int mi = 0; mi < 2; mi++) {
      float pm[4], fac[4], rsum[4];
#pragma unroll
      for (int r = 0; r < 4; r++) {
        pm[r] = fmaxf(fmaxf(s[mi][0][r], s[mi][1][r]), fmaxf(s[mi][2][r], s[mi][3][r]));
#pragma unroll
        for (int mk = 1; mk < 16; mk <<= 1) pm[r] = fmaxf(pm[r], __shfl_xor(pm[r], mk));
        float mn = fmaxf(mrun[mi][r], pm[r]);
        fac[r] = exp2f(mrun[mi][r] - mn);
        mrun[mi][r] = mn;
        rsum[r] = 0.f;
      }
#pragma unroll
      for (int n = 0; n < 4; n++)
#pragma unroll
        for (int r = 0; r < 4; r++) {
          float p = exp2f(s[mi][n][r] - mrun[mi][r]);
          s[mi][n][r] = p;
          rsum[r] += p;
        }
#pragma unroll
      for (int r = 0; r < 4; r++) {
#pragma unroll
        for (int mk = 1; mk < 16; mk <<= 1) rsum[r] += __shfl_xor(rsum[r], mk);
        lrun[mi][r] = lrun[mi][r] * fac[r] + rsum[r];
      }
#pragma unroll
      for (int n = 0; n < 4; n++)
#pragma unroll
        for (int r = 0; r < 4; r++) o[mi][n][r] *= fac[r];
      // stash P for transpose (per-wave LDS; no barrier needed)
#pragma unroll
      for (int n = 0; n < 4; n++)
#pragma unroll
        for (int r = 0; r < 4; r++)
          Ps[w][mi * 16 + lg * 4 + r][n * 16 + lr] = bf16_of(s[mi][n][r]);
    }
    // V fragments straight from L2, then PV
    short8 bv[2][4];
#pragma unroll
    for (int n = 0; n < 4; n++) {
      int dh = n * 16 + lr;
#pragma unroll
      for (int st = 0; st < 2; st++)
        bv[st][n] = *(const short8*)&vb[(size_t)dh * T_ + kbase + st * 32 + lg * 8];
    }
#pragma unroll
    for (int mi = 0; mi < 2; mi++) {
      short8 ap[2];
#pragma unroll
      for (int st = 0; st < 2; st++)
        ap[st] = *(const short8*)&Ps[w][mi * 16 + lr][st * 32 + lg * 8];
#pragma unroll
      for (int st = 0; st < 2; st++)
#pragma unroll
        for (int n = 0; n < 4; n++)
          o[mi][n] = mfma_bf16(ap[st], bv[st][n], o[mi][n]);
    }
  }
  // epilogue
  const int b = bh >> 4, h = bh & 15;
#pragma unroll
  for (int mi = 0; mi < 2; mi++)
#pragma unroll
    for (int n = 0; n < 4; n++)
#pragma unroll
      for (int r = 0; r < 4; r++) {
        int tq = qi * 128 + w * 32 + mi * 16 + lg * 4 + r;
        if (tq < T_) {
          float val = o[mi][n][r] / lrun[mi][r];
          ctx[((size_t)(b * T_ + tq)) * D_ + h * HD_ + n * 16 + lr] = bf16_of(val);
        }
      }
}

// ---------------- output projection + residual + splits (128-tile) ----------------
__global__ __launch_bounds__(256) void k_out(
    const unsigned short* __restrict__ ctxb, const unsigned short* __restrict__ Wob,
    const float* __restrict__ bo, const float* __restrict__ tokens,
    const float* __restrict__ memory, float* __restrict__ out_tok,
    unsigned short* __restrict__ tokb, unsigned short* __restrict__ tokTb,
    float* __restrict__ memout, unsigned short* __restrict__ comb) {
  f32x4 acc[4][4];
  const int m0 = blockIdx.y * 128, n0 = blockIdx.x * 128;
  gemm128_core(ctxb, Wob, D_, m0, n0, acc);
  const int tid = threadIdx.x, w = tid >> 6, l = tid & 63;
  const int wr = w >> 1, wc = w & 1;
#pragma unroll
  for (int i = 0; i < 4; i++) {
#pragma unroll
    for (int j = 0; j < 4; j++) {
#pragma unroll
      for (int r = 0; r < 4; r++) {
        int m = m0 + wr * 64 + i * 16 + (l >> 4) * 4 + r;
        int c = n0 + wc * 64 + j * 16 + (l & 15);
        int b = m / T_, t = m - b * T_;
        float xo = (t < M_) ? memory[((size_t)b * M_ + t) * D_ + c]
                            : tokens[((size_t)b * S_ + (t - M_)) * D_ + c];
        float val = acc[i][j][r] + bo[c] + xo;
        if (t < M_) {
          memout[((size_t)b * M_ + t) * D_ + c] = val;
          comb[((size_t)b * M_ + t) * (2 * D_) + c] = bf16_of(val);
        } else {
          size_t ti = (size_t)b * S_ + (t - M_);
          out_tok[ti * D_ + c] = val;
          tokb[ti * D_ + c] = bf16_of(val);
          tokTb[((size_t)b * D_ + c) * S_ + (t - M_)] = bf16_of(val);
        }
      }
    }
  }
}

// ---------------- pool scores: split-K partials ----------------
// grid (32 s-tiles, 4 ksplit, 2 b); pscp[ks][b][64][S_]
__global__ __launch_bounds__(256) void k_pscore_part(
    const unsigned short* __restrict__ pqb, const unsigned short* __restrict__ tokb,
    float* __restrict__ pscp) {
  const int stile = blockIdx.x, ks = blockIdx.y, b = blockIdx.z;
  f32x4 acc[4];
  gemm_core(pqb + ks * 256, tokb + (size_t)b * S_ * D_ + ks * 256, D_, 256,
            0, stile * 64, acc);
  const int tid = threadIdx.x, w = tid >> 6, l = tid & 63;
  float* dst = pscp + ((size_t)(ks * B_ + b) * M_) * S_;
#pragma unroll
  for (int n = 0; n < 4; n++) {
#pragma unroll
    for (int r = 0; r < 4; r++) {
      int m = w * 16 + (l >> 4) * 4 + r;
      int s = stile * 64 + n * 16 + (l & 15);
      dst[(size_t)m * S_ + s] = acc[n][r];
    }
  }
}

// ---------------- pool softmax (sums 4 partials; exp2 domain) ----------------
__global__ __launch_bounds__(256) void k_psoftmax(const float* __restrict__ pscp,
                                                  unsigned short* __restrict__ pw) {
  const int row = blockIdx.x;          // b*64 + m
  const int b = row >> 6, m = row & 63;
  const int tid = threadIdx.x;
  float v[8];
  float mx = -1e30f;
#pragma unroll
  for (int i = 0; i < 8; i++) {
    int s = tid + i * 256;
    float acc = 0.f;
#pragma unroll
    for (int ks = 0; ks < 4; ks++)
      acc += pscp[((size_t)(ks * B_ + b) * M_ + m) * S_ + s];
    v[i] = acc;
    mx = fmaxf(mx, acc);
  }
#pragma unroll
  for (int off = 1; off < 64; off <<= 1) mx = fmaxf(mx, __shfl_xor(mx, off));
  __shared__ float rm[4], rs[4];
  if ((tid & 63) == 0) rm[tid >> 6] = mx;
  __syncthreads();
  mx = fmaxf(fmaxf(rm[0], rm[1]), fmaxf(rm[2], rm[3]));
  float sum = 0.f;
#pragma unroll
  for (int i = 0; i < 8; i++) {
    v[i] = exp2f(v[i] - mx);
    sum += v[i];
  }
#pragma unroll
  for (int off = 1; off < 64; off <<= 1) sum += __shfl_xor(sum, off);
  if ((tid & 63) == 0) rs[tid >> 6] = sum;
  __syncthreads();
  float inv = 1.f / (rs[0] + rs[1] + rs[2] + rs[3]);
#pragma unroll
  for (int i = 0; i < 8; i++)
    pw[(size_t)row * S_ + tid + i * 256] = bf16_of(v[i] * inv);
}

// ---------------- summary: split-K partials ----------------
// grid (16 d-tiles, 8 ksplit, 2 b); sump[ks][b][64][D_]
__global__ __launch_bounds__(256) void k_summary_part(
    const unsigned short* __restrict__ pw, const unsigned short* __restrict__ tokTb,
    float* __restrict__ sump) {
  const int nt = blockIdx.x, ks = blockIdx.y, b = blockIdx.z;
  f32x4 acc[4];
  gemm_core(pw + (size_t)b * M_ * S_ + ks * 256,
            tokTb + (size_t)b * D_ * S_ + ks * 256, S_, 256, 0, nt * 64, acc);
  const int tid = threadIdx.x, w = tid >> 6, l = tid & 63;
  float* dst = sump + ((size_t)(ks * B_ + b) * M_) * D_;
#pragma unroll
  for (int n = 0; n < 4; n++) {
#pragma unroll
    for (int r = 0; r < 4; r++) {
      int m = w * 16 + (l >> 4) * 4 + r;
      int c = nt * 64 + n * 16 + (l & 15);
      dst[(size_t)m * D_ + c] = acc[n][r];
    }
  }
}

// combine summary partials -> comb[:, D_:]
__global__ void k_sumcomb(const float* __restrict__ sump,
                          unsigned short* __restrict__ comb) {
  int i = blockIdx.x * blockDim.x + threadIdx.x;
  if (i >= B_ * M_ * D_) return;
  int bm = i >> 10, c = i & 1023;
  int b = bm >> 6, m = bm & 63;
  float acc = 0.f;
#pragma unroll
  for (int ks = 0; ks < 8; ks++)
    acc += sump[((size_t)(ks * B_ + b) * M_ + m) * D_ + c];
  comb[((size_t)b * M_ + m) * (2 * D_) + D_ + c] = bf16_of(acc);
}

// ---------------- cell GEMM: split-K partials ----------------
// grid (32 n-tiles, 2 m-tiles, 4 ksplit); cellp[ks][128][2048]
__global__ __launch_bounds__(256) void k_cell_part(
    const unsigned short* __restrict__ comb, const unsigned short* __restrict__ cWb,
    float* __restrict__ cellp) {
  const int nt = blockIdx.x, mt = blockIdx.y, ks = blockIdx.z;
  f32x4 acc[4];
  gemm_core(comb + ks * 512, cWb + ks * 512, 2 * D_, 512, mt * 64, nt * 64, acc);
  const int tid = threadIdx.x, w = tid >> 6, l = tid & 63;
#pragma unroll
  for (int n = 0; n < 4; n++) {
#pragma unroll
    for (int r = 0; r < 4; r++) {
      int m = mt * 64 + w * 16 + (l >> 4) * 4 + r;
      int c = nt * 64 + n * 16 + (l & 15);
      cellp[((size_t)ks * (B_ * M_) + m) * (2 * D_) + c] = acc[n][r];
    }
  }
}

// ---------------- final gating (sums 4 cell partials + bias) ----------------
__global__ void k_newmem(const float* __restrict__ cellp,
                         const float* __restrict__ cb,
                         const float* __restrict__ memout,
                         float* __restrict__ out2) {
  int i = blockIdx.x * blockDim.x + threadIdx.x;
  if (i >= B_ * M_ * D_) return;
  int r = i >> 10, d = i & 1023;
  float gsum = cb[d], csum = cb[D_ + d];
#pragma unroll
  for (int ks = 0; ks < 4; ks++) {
    gsum += cellp[((size_t)ks * (B_ * M_) + r) * (2 * D_) + d];
    csum += cellp[((size_t)ks * (B_ * M_) + r) * (2 * D_) + D_ + d];
  }
  float sg = 1.f / (1.f + __expf(-gsum));
  float sc = 1.f / (1.f + __expf(-csum));
  out2[i] = memout[i] * sg + (1.f - sg) * (csum * sc);
}

// ---------------- launch ----------------
extern "C" void kernel_launch(void* const* d_in, const int* in_sizes, int n_in,
                              void* d_out, int out_size, void* d_ws, size_t ws_size,
                              hipStream_t stream) {
  const float* tokens = (const float*)d_in[0];
  const float* memory = (const float*)d_in[1];
  const float* Wq = (const float*)d_in[2];
  const float* bq = (const float*)d_in[3];
  const float* Wk = (const float*)d_in[4];
  const float* bk = (const float*)d_in[5];
  const float* Wv = (const float*)d_in[6];
  const float* bv = (const float*)d_in[7];
  const float* Wo = (const float*)d_in[8];
  const float* bo = (const float*)d_in[9];
  const float* pool_q = (const float*)d_in[10];
  const float* cell_W = (const float*)d_in[11];
  const float* cell_b = (const float*)d_in[12];

  size_t off = 0;
  auto alloc = [&](size_t bytes) -> void* {
    void* p = (char*)d_ws + off;
    off += (bytes + 255) & ~(size_t)255;
    return p;
  };
  unsigned short* xb    = (unsigned short*)alloc((size_t)BT_ * D_ * 2);
  unsigned short* Wqb   = (unsigned short*)alloc((size_t)D_ * D_ * 2);
  unsigned short* Wkb   = (unsigned short*)alloc((size_t)D_ * D_ * 2);
  unsigned short* Wvb   = (unsigned short*)alloc((size_t)D_ * D_ * 2);
  unsigned short* Wob   = (unsigned short*)alloc((size_t)D_ * D_ * 2);
  unsigned short* cWb   = (unsigned short*)alloc((size_t)(2 * D_) * (2 * D_) * 2);
  unsigned short* pqb   = (unsigned short*)alloc((size_t)M_ * D_ * 2);
  unsigned short* qg    = (unsigned short*)alloc((size_t)B_ * H_ * T_ * HD_ * 2);
  unsigned short* kg    = (unsigned short*)alloc((size_t)B_ * H_ * T_ * HD_ * 2);
  unsigned short* vTg   = (unsigned short*)alloc((size_t)B_ * H_ * HD_ * T_ * 2);
  unsigned short* ctxb  = (unsigned short*)alloc((size_t)BT_ * D_ * 2);
  unsigned short* tokb  = (unsigned short*)alloc((size_t)B_ * S_ * D_ * 2);
  unsigned short* tokTb = (unsigned short*)alloc((size_t)B_ * D_ * S_ * 2);
  float*          memout= (float*)alloc((size_t)B_ * M_ * D_ * 4);
  unsigned short* comb  = (unsigned short*)alloc((size_t)B_ * M_ * 2 * D_ * 2);
  unsigned short* pwt   = (unsigned short*)alloc((size_t)B_ * M_ * S_ * 2);
  float*          pscp  = (float*)alloc((size_t)4 * B_ * M_ * S_ * 4);
  float*          sump  = (float*)alloc((size_t)8 * B_ * M_ * D_ * 4);
  float*          cellp = (float*)alloc((size_t)4 * B_ * M_ * 2 * D_ * 4);

  float* out_tok = (float*)d_out;
  float* out_mem = out_tok + (size_t)B_ * S_ * D_;

  k_build_x<<<2048, 256, 0, stream>>>(tokens, memory, xb);
  k_cast_all<<<4096, 256, 0, stream>>>(Wq, Wk, Wv, Wo, cell_W, pool_q,
                                       Wqb, Wkb, Wvb, Wob, cWb, pqb);

  k_qkv<<<dim3(8, 33, 3), 256, 0, stream>>>(xb, Wqb, Wkb, Wvb, bq, bk, bv, qg, kg, vTg);
  k_attn<<<544, 256, 0, stream>>>(qg, kg, vTg, ctxb);
  k_out<<<dim3(8, 33), 256, 0, stream>>>(ctxb, Wob, bo, tokens, memory, out_tok,
                                         tokb, tokTb, memout, comb);
  k_pscore_part<<<dim3(32, 4, 2), 256, 0, stream>>>(pqb, tokb, pscp);
  k_psoftmax<<<B_ * M_, 256, 0, stream>>>(pscp, pwt);
  k_summary_part<<<dim3(16, 8, 2), 256, 0, stream>>>(pwt, tokTb, sump);
  k_sumcomb<<<512, 256, 0, stream>>>(sump, comb);
  k_cell_part<<<dim3(32, 2, 4), 256, 0, stream>>>(comb, cWb, cellp);
  k_newmem<<<512, 256, 0, stream>>>(cellp, cell_b, memout, out_mem);
}

// Round 4
// 296.680 us; speedup vs baseline: 1.1707x; 1.1707x over previous
//
#include <hip/hip_runtime.h>
#include <hip/hip_bf16.h>

#define B_  2
#define S_  2048
#define M_  64
#define D_  1024
#define T_  2112      // M_ + S_
#define H_  16
#define HD_ 64
#define BT_ (B_*T_)   // 4224
#define NEGBIG (-1e9f)
#define LOG2E 1.44269504f

typedef float f32x4  __attribute__((ext_vector_type(4)));
typedef short short8 __attribute__((ext_vector_type(8)));
typedef __bf16 bf16x8 __attribute__((ext_vector_type(8)));

static __device__ __forceinline__ unsigned short bf16_of(float f) {
  __hip_bfloat16 h = __float2bfloat16(f);
  return __builtin_bit_cast(unsigned short, h);
}

static __device__ __forceinline__ f32x4 mfma_bf16(short8 a, short8 b, f32x4 c) {
  return __builtin_amdgcn_mfma_f32_16x16x32_bf16(
      __builtin_bit_cast(bf16x8, a), __builtin_bit_cast(bf16x8, b), c, 0, 0, 0);
}

// async global->LDS, 16B per lane; lds base must be wave-uniform (lane adds l*16).
static __device__ __forceinline__ void gload16(const void* g, void* lds) {
  __builtin_amdgcn_global_load_lds(
      (const __attribute__((address_space(1))) unsigned int*)g,
      (__attribute__((address_space(3))) unsigned int*)lds, 16, 0, 0);
}

// ---------------- cast / concat kernels ----------------

__global__ void k_build_x(const float* __restrict__ tokens,
                          const float* __restrict__ memory,
                          unsigned short* __restrict__ xb) {
  for (int i = blockIdx.x * blockDim.x + threadIdx.x; i < BT_ * D_;
       i += gridDim.x * blockDim.x) {
    int b = i / (T_ * D_);
    int rem = i - b * (T_ * D_);
    int t = rem / D_;
    int d = rem - t * D_;
    float v = (t < M_) ? memory[((size_t)b * M_ + t) * D_ + d]
                       : tokens[((size_t)b * S_ + (t - M_)) * D_ + d];
    xb[i] = bf16_of(v);
  }
}

// casts: Wq,Wk,Wv -> contiguous Wqkvb (3x1M), Wo (1M), cell_W (4M), pool_q (64K scaled)
__global__ void k_cast_all(const float* __restrict__ Wq, const float* __restrict__ Wk,
                           const float* __restrict__ Wv, const float* __restrict__ Wo,
                           const float* __restrict__ cW, const float* __restrict__ pq,
                           unsigned short* __restrict__ Wqkvb, unsigned short* __restrict__ Wob,
                           unsigned short* __restrict__ cWb, unsigned short* __restrict__ pqb) {
  const int NW = D_ * D_;            // 1M
  const int NC = 4 * D_ * D_;        // 4M
  const int NP = M_ * D_;            // 64K
  const int total = 4 * NW + NC + NP;
  for (int i = blockIdx.x * blockDim.x + threadIdx.x; i < total;
       i += gridDim.x * blockDim.x) {
    if (i < 3 * NW) {
      int which = i >> 20, j = i & (NW - 1);
      const float* s = (which == 0) ? Wq : (which == 1) ? Wk : Wv;
      Wqkvb[i] = bf16_of(s[j]);
    } else if (i < 4 * NW) {
      int j = i - 3 * NW;
      Wob[j] = bf16_of(Wo[j]);
    } else if (i < 4 * NW + NC) {
      int j = i - 4 * NW;
      cWb[j] = bf16_of(cW[j]);
    } else {
      int j = i - 4 * NW - NC;
      pqb[j] = bf16_of(pq[j] * 0.03125f * LOG2E);   // D^-0.5, exp2-domain
    }
  }
}

// ---------------- 128x128 GEMM core (m97 structure) ----------------
__device__ __forceinline__ void gemm128_core(const unsigned short* __restrict__ A,
                                             const unsigned short* __restrict__ BT,
                                             int K, int m0, int n0,
                                             f32x4 acc[4][4]) {
  __shared__ __align__(16) unsigned short As[128][32];
  __shared__ __align__(16) unsigned short Bs[128][32];
  const int tid = threadIdx.x;
  const int w = tid >> 6, l = tid & 63;
  const int wr = w >> 1, wc = w & 1;
  const int srow = l >> 2;
  const int scol = (l & 3) * 8;
  f32x4 z; z[0] = z[1] = z[2] = z[3] = 0.f;
#pragma unroll
  for (int i = 0; i < 4; i++)
#pragma unroll
    for (int j = 0; j < 4; j++) acc[i][j] = z;

  for (int k0 = 0; k0 < K; k0 += 32) {
    __syncthreads();
#pragma unroll
    for (int c = 0; c < 2; c++) {
      int rbase = w * 32 + c * 16;
      gload16(&A[(size_t)(m0 + rbase + srow) * K + k0 + scol], &As[rbase][0]);
      gload16(&BT[(size_t)(n0 + rbase + srow) * K + k0 + scol], &Bs[rbase][0]);
    }
    __syncthreads();
    short8 a[4], b[4];
#pragma unroll
    for (int i = 0; i < 4; i++)
      a[i] = *(const short8*)&As[wr * 64 + i * 16 + (l & 15)][(l >> 4) * 8];
#pragma unroll
    for (int j = 0; j < 4; j++)
      b[j] = *(const short8*)&Bs[wc * 64 + j * 16 + (l & 15)][(l >> 4) * 8];
#pragma unroll
    for (int i = 0; i < 4; i++)
#pragma unroll
      for (int j = 0; j < 4; j++)
        acc[i][j] = mfma_bf16(a[i], b[j], acc[i][j]);
  }
}

// ---------------- small 64x64 GEMM core (partial-K capable) ----------------
__device__ __forceinline__ void gemm_core(const unsigned short* __restrict__ A,
                                          const unsigned short* __restrict__ BT,
                                          int ldk, int Klen, int m0, int n0,
                                          f32x4 acc[4]) {
  __shared__ __align__(16) unsigned short As[64][40];
  __shared__ __align__(16) unsigned short Bs[64][40];
  const int tid = threadIdx.x;
  const int w = tid >> 6, l = tid & 63;
  const int sr = tid >> 2, sc = (tid & 3) * 8;
  f32x4 z; z[0] = z[1] = z[2] = z[3] = 0.f;
  acc[0] = acc[1] = acc[2] = acc[3] = z;
  for (int k0 = 0; k0 < Klen; k0 += 32) {
    __syncthreads();
    *(short8*)&As[sr][sc] = *(const short8*)&A[(size_t)(m0 + sr) * ldk + k0 + sc];
    *(short8*)&Bs[sr][sc] = *(const short8*)&BT[(size_t)(n0 + sr) * ldk + k0 + sc];
    __syncthreads();
    short8 a = *(const short8*)&As[w * 16 + (l & 15)][(l >> 4) * 8];
#pragma unroll
    for (int n = 0; n < 4; n++) {
      short8 b = *(const short8*)&Bs[n * 16 + (l & 15)][(l >> 4) * 8];
      acc[n] = mfma_bf16(a, b, acc[n]);
    }
  }
}

// ---------------- fused QKV projection (128-tile, single launch) ----------------
// grid: x = n-tile (24: 8 per Q/K/V), y = m-tile (33). which = bx>>3.
__global__ __launch_bounds__(256) void k_qkv(
    const unsigned short* __restrict__ xb, const unsigned short* __restrict__ Wqkvb,
    const float* __restrict__ bq, const float* __restrict__ bk,
    const float* __restrict__ bv, unsigned short* __restrict__ qg,
    unsigned short* __restrict__ kg, unsigned short* __restrict__ vTg) {
  const int which = blockIdx.x >> 3;
  const unsigned short* W = Wqkvb + (size_t)which * D_ * D_;
  const float* bias = (which == 0) ? bq : ((which == 1) ? bk : bv);
  f32x4 acc[4][4];
  const int m0 = blockIdx.y * 128, n0 = (blockIdx.x & 7) * 128;
  gemm128_core(xb, W, D_, m0, n0, acc);
  const int tid = threadIdx.x, w = tid >> 6, l = tid & 63;
  const int wr = w >> 1, wc = w & 1;
#pragma unroll
  for (int i = 0; i < 4; i++) {
#pragma unroll
    for (int j = 0; j < 4; j++) {
#pragma unroll
      for (int r = 0; r < 4; r++) {
        int m = m0 + wr * 64 + i * 16 + (l >> 4) * 4 + r;
        int c = n0 + wc * 64 + j * 16 + (l & 15);
        int b = m / T_, t = m - b * T_;
        int h = c >> 6, dh = c & 63;
        int bh = b * H_ + h;
        float v = acc[i][j][r] + bias[c];
        if (which == 0)
          qg[((size_t)bh * T_ + t) * HD_ + dh] = bf16_of(v * 0.125f * LOG2E);
        else if (which == 1)
          kg[((size_t)bh * T_ + t) * HD_ + dh] = bf16_of(v);
        else
          vTg[((size_t)bh * HD_ + dh) * T_ + t] = bf16_of(v);
      }
    }
  }
}

// ---------------- fused attention: dbuf LDS staging via global_load_lds ----------------
// grid: 544 blocks 1D.  id = 8*((bh/8)*17 + (16-qi)) + bh%8 (bh-group -> XCD, heavy first).
// Block = 4 waves; wave w owns 32 q-rows [qi*128 + w*32, +32) (2 sub-tiles of 16).
// K/V tiles staged with XOR-swizzled source (unit ^= row&7), read with same XOR.
__global__ __launch_bounds__(256) void k_attn(
    const unsigned short* __restrict__ qg, const unsigned short* __restrict__ kg,
    const unsigned short* __restrict__ vTg, unsigned short* __restrict__ ctx) {
  const int id = blockIdx.x;
  const int xcd = id & 7;
  const int rem = id >> 3;
  const int g = rem / 17, qir = rem - g * 17;
  const int qi = 16 - qir;
  const int bh = g * 8 + xcd;
  const int tid = threadIdx.x, w = tid >> 6, l = tid & 63;
  const int lr = l & 15, lg = l >> 4;
  __shared__ __align__(16) unsigned short Ks[2][64][64];
  __shared__ __align__(16) unsigned short Vs[2][64][64];
  __shared__ __align__(16) unsigned short Ps[4][32][72];

  const unsigned short* qb = qg + (size_t)bh * T_ * HD_;
  const unsigned short* kb = kg + (size_t)bh * T_ * HD_;
  const unsigned short* vb = vTg + (size_t)bh * HD_ * T_;

  // q fragments: 2 sub-tiles x 2 k-steps
  short8 aq[2][2];
#pragma unroll
  for (int mi = 0; mi < 2; mi++) {
    int tq = qi * 128 + w * 32 + mi * 16 + lr;
    int tqc = tq < T_ ? tq : T_ - 1;
#pragma unroll
    for (int st = 0; st < 2; st++)
      aq[mi][st] = *(const short8*)&qb[(size_t)tqc * HD_ + st * 32 + lg * 8];
  }

  f32x4 zz; zz[0] = zz[1] = zz[2] = zz[3] = 0.f;
  f32x4 o[2][4];
  float mrun[2][4], lrun[2][4];
#pragma unroll
  for (int mi = 0; mi < 2; mi++)
#pragma unroll
    for (int n = 0; n < 4; n++) o[mi][n] = zz;
#pragma unroll
  for (int mi = 0; mi < 2; mi++)
#pragma unroll
    for (int r = 0; r < 4; r++) { mrun[mi][r] = -1e30f; lrun[mi][r] = 0.f; }

  const int nkt = (qi == 0) ? 33 : ((2 * qi + 2 < 33) ? 2 * qi + 2 : 33);
  const int qmin = (qi == 0) ? M_ : qi * 128;

  // stage tile starting at column kb2 into buffer buf (16KB via 16 gload16/block)
  auto stage = [&](int buf, int kb2) {
#pragma unroll
    for (int i = 0; i < 2; i++) {
      int rr = w * 16 + i * 8 + (l >> 3);            // row within 64-tile
      int swz = ((l & 7) ^ (rr & 7)) * 8;            // swizzled 16B-unit (elems)
      gload16(&kb[(size_t)(kb2 + rr) * HD_ + swz], &Ks[buf][w * 16 + i * 8][0]);
      gload16(&vb[(size_t)rr * T_ + kb2 + swz], &Vs[buf][w * 16 + i * 8][0]);
    }
  };

  stage(0, 0);
  __syncthreads();
  int cur = 0;

  for (int j = 0; j < nkt; j++) {
    const int kbase = j * 64;
    if (j + 1 < nkt) stage(cur ^ 1, kbase + 64);     // async prefetch next tile

    // K fragments from LDS (swizzled read)
    short8 bkf[2][4];
#pragma unroll
    for (int n = 0; n < 4; n++) {
      int row = n * 16 + lr;
      int sw = lr & 7;
#pragma unroll
      for (int st = 0; st < 2; st++)
        bkf[st][n] = *(const short8*)&Ks[cur][row][((st * 4 + lg) ^ sw) * 8];
    }
    f32x4 s[2][4];
#pragma unroll
    for (int mi = 0; mi < 2; mi++)
#pragma unroll
      for (int n = 0; n < 4; n++) s[mi][n] = zz;
#pragma unroll
    for (int st = 0; st < 2; st++)
#pragma unroll
      for (int mi = 0; mi < 2; mi++)
#pragma unroll
        for (int n = 0; n < 4; n++)
          s[mi][n] = mfma_bf16(aq[mi][st], bkf[st][n], s[mi][n]);

    // causal mask (memory rows tq<M_ attend everywhere)
    if (kbase + 63 > qmin) {
#pragma unroll
      for (int mi = 0; mi < 2; mi++)
#pragma unroll
        for (int n = 0; n < 4; n++)
#pragma unroll
          for (int r = 0; r < 4; r++) {
            int tq = qi * 128 + w * 32 + mi * 16 + lg * 4 + r;
            int tk = kbase + n * 16 + lr;
            if (tq >= M_ && tk > tq) s[mi][n][r] = NEGBIG;
          }
    }
    // online softmax in exp2 domain (scale pre-folded into q)
#pragma unroll
    for (int mi = 0; mi < 2; mi++) {
      float pm[4], fac[4], rsum[4];
#pragma unroll
      for (int r = 0; r < 4; r++) {
        pm[r] = fmaxf(fmaxf(s[mi][0][r], s[mi][1][r]), fmaxf(s[mi][2][r], s[mi][3][r]));
#pragma unroll
        for (int mk = 1; mk < 16; mk <<= 1) pm[r] = fmaxf(pm[r], __shfl_xor(pm[r], mk));
        float mn = fmaxf(mrun[mi][r], pm[r]);
        fac[r] = exp2f(mrun[mi][r] - mn);
        mrun[mi][r] = mn;
        rsum[r] = 0.f;
      }
#pragma unroll
      for (int n = 0; n < 4; n++)
#pragma unroll
        for (int r = 0; r < 4; r++) {
          float p = exp2f(s[mi][n][r] - mrun[mi][r]);
          s[mi][n][r] = p;
          rsum[r] += p;
        }
#pragma unroll
      for (int r = 0; r < 4; r++) {
#pragma unroll
        for (int mk = 1; mk < 16; mk <<= 1) rsum[r] += __shfl_xor(rsum[r], mk);
        lrun[mi][r] = lrun[mi][r] * fac[r] + rsum[r];
      }
#pragma unroll
      for (int n = 0; n < 4; n++)
#pragma unroll
        for (int r = 0; r < 4; r++) o[mi][n][r] *= fac[r];
      // stash P (per-wave LDS; no barrier needed)
#pragma unroll
      for (int n = 0; n < 4; n++)
#pragma unroll
        for (int r = 0; r < 4; r++)
          Ps[w][mi * 16 + lg * 4 + r][n * 16 + lr] = bf16_of(s[mi][n][r]);
    }
    // V fragments from LDS (swizzled read), then PV
    short8 bvf[2][4];
#pragma unroll
    for (int n = 0; n < 4; n++) {
      int row = n * 16 + lr;                          // dh
      int sw = lr & 7;
#pragma unroll
      for (int st = 0; st < 2; st++)
        bvf[st][n] = *(const short8*)&Vs[cur][row][((st * 4 + lg) ^ sw) * 8];
    }
#pragma unroll
    for (int mi = 0; mi < 2; mi++) {
      short8 ap[2];
#pragma unroll
      for (int st = 0; st < 2; st++)
        ap[st] = *(const short8*)&Ps[w][mi * 16 + lr][st * 32 + lg * 8];
#pragma unroll
      for (int st = 0; st < 2; st++)
#pragma unroll
        for (int n = 0; n < 4; n++)
          o[mi][n] = mfma_bf16(ap[st], bvf[st][n], o[mi][n]);
    }
    __syncthreads();   // drains this iter's prefetch (vmcnt) + guards buffer reuse
    cur ^= 1;
  }
  // epilogue
  const int b = bh >> 4, h = bh & 15;
#pragma unroll
  for (int mi = 0; mi < 2; mi++)
#pragma unroll
    for (int n = 0; n < 4; n++)
#pragma unroll
      for (int r = 0; r < 4; r++) {
        int tq = qi * 128 + w * 32 + mi * 16 + lg * 4 + r;
        if (tq < T_) {
          float val = o[mi][n][r] / lrun[mi][r];
          ctx[((size_t)(b * T_ + tq)) * D_ + h * HD_ + n * 16 + lr] = bf16_of(val);
        }
      }
}

// ---------------- output projection + residual + splits (128-tile) ----------------
__global__ __launch_bounds__(256) void k_out(
    const unsigned short* __restrict__ ctxb, const unsigned short* __restrict__ Wob,
    const float* __restrict__ bo, const float* __restrict__ tokens,
    const float* __restrict__ memory, float* __restrict__ out_tok,
    unsigned short* __restrict__ tokb, unsigned short* __restrict__ tokTb,
    float* __restrict__ memout, unsigned short* __restrict__ comb) {
  f32x4 acc[4][4];
  const int m0 = blockIdx.y * 128, n0 = blockIdx.x * 128;
  gemm128_core(ctxb, Wob, D_, m0, n0, acc);
  const int tid = threadIdx.x, w = tid >> 6, l = tid & 63;
  const int wr = w >> 1, wc = w & 1;
#pragma unroll
  for (int i = 0; i < 4; i++) {
#pragma unroll
    for (int j = 0; j < 4; j++) {
#pragma unroll
      for (int r = 0; r < 4; r++) {
        int m = m0 + wr * 64 + i * 16 + (l >> 4) * 4 + r;
        int c = n0 + wc * 64 + j * 16 + (l & 15);
        int b = m / T_, t = m - b * T_;
        float xo = (t < M_) ? memory[((size_t)b * M_ + t) * D_ + c]
                            : tokens[((size_t)b * S_ + (t - M_)) * D_ + c];
        float val = acc[i][j][r] + bo[c] + xo;
        if (t < M_) {
          memout[((size_t)b * M_ + t) * D_ + c] = val;
          comb[((size_t)b * M_ + t) * (2 * D_) + c] = bf16_of(val);
        } else {
          size_t ti = (size_t)b * S_ + (t - M_);
          out_tok[ti * D_ + c] = val;
          tokb[ti * D_ + c] = bf16_of(val);
          tokTb[((size_t)b * D_ + c) * S_ + (t - M_)] = bf16_of(val);
        }
      }
    }
  }
}

// ---------------- pool scores: split-K partials ----------------
__global__ __launch_bounds__(256) void k_pscore_part(
    const unsigned short* __restrict__ pqb, const unsigned short* __restrict__ tokb,
    float* __restrict__ pscp) {
  const int stile = blockIdx.x, ks = blockIdx.y, b = blockIdx.z;
  f32x4 acc[4];
  gemm_core(pqb + ks * 256, tokb + (size_t)b * S_ * D_ + ks * 256, D_, 256,
            0, stile * 64, acc);
  const int tid = threadIdx.x, w = tid >> 6, l = tid & 63;
  float* dst = pscp + ((size_t)(ks * B_ + b) * M_) * S_;
#pragma unroll
  for (int n = 0; n < 4; n++) {
#pragma unroll
    for (int r = 0; r < 4; r++) {
      int m = w * 16 + (l >> 4) * 4 + r;
      int s = stile * 64 + n * 16 + (l & 15);
      dst[(size_t)m * S_ + s] = acc[n][r];
    }
  }
}

// ---------------- pool softmax (sums 4 partials; exp2 domain) ----------------
__global__ __launch_bounds__(256) void k_psoftmax(const float* __restrict__ pscp,
                                                  unsigned short* __restrict__ pw) {
  const int row = blockIdx.x;          // b*64 + m
  const int b = row >> 6, m = row & 63;
  const int tid = threadIdx.x;
  float v[8];
  float mx = -1e30f;
#pragma unroll
  for (int i = 0; i < 8; i++) {
    int s = tid + i * 256;
    float acc = 0.f;
#pragma unroll
    for (int ks = 0; ks < 4; ks++)
      acc += pscp[((size_t)(ks * B_ + b) * M_ + m) * S_ + s];
    v[i] = acc;
    mx = fmaxf(mx, acc);
  }
#pragma unroll
  for (int off = 1; off < 64; off <<= 1) mx = fmaxf(mx, __shfl_xor(mx, off));
  __shared__ float rm[4], rs[4];
  if ((tid & 63) == 0) rm[tid >> 6] = mx;
  __syncthreads();
  mx = fmaxf(fmaxf(rm[0], rm[1]), fmaxf(rm[2], rm[3]));
  float sum = 0.f;
#pragma unroll
  for (int i = 0; i < 8; i++) {
    v[i] = exp2f(v[i] - mx);
    sum += v[i];
  }
#pragma unroll
  for (int off = 1; off < 64; off <<= 1) sum += __shfl_xor(sum, off);
  if ((tid & 63) == 0) rs[tid >> 6] = sum;
  __syncthreads();
  float inv = 1.f / (rs[0] + rs[1] + rs[2] + rs[3]);
#pragma unroll
  for (int i = 0; i < 8; i++)
    pw[(size_t)row * S_ + tid + i * 256] = bf16_of(v[i] * inv);
}

// ---------------- summary: split-K partials ----------------
__global__ __launch_bounds__(256) void k_summary_part(
    const unsigned short* __restrict__ pw, const unsigned short* __restrict__ tokTb,
    float* __restrict__ sump) {
  const int nt = blockIdx.x, ks = blockIdx.y, b = blockIdx.z;
  f32x4 acc[4];
  gemm_core(pw + (size_t)b * M_ * S_ + ks * 256,
            tokTb + (size_t)b * D_ * S_ + ks * 256, S_, 256, 0, nt * 64, acc);
  const int tid = threadIdx.x, w = tid >> 6, l = tid & 63;
  float* dst = sump + ((size_t)(ks * B_ + b) * M_) * D_;
#pragma unroll
  for (int n = 0; n < 4; n++) {
#pragma unroll
    for (int r = 0; r < 4; r++) {
      int m = w * 16 + (l >> 4) * 4 + r;
      int c = nt * 64 + n * 16 + (l & 15);
      dst[(size_t)m * D_ + c] = acc[n][r];
    }
  }
}

// combine summary partials -> comb[:, D_:]
__global__ void k_sumcomb(const float* __restrict__ sump,
                          unsigned short* __restrict__ comb) {
  int i = blockIdx.x * blockDim.x + threadIdx.x;
  if (i >= B_ * M_ * D_) return;
  int bm = i >> 10, c = i & 1023;
  int b = bm >> 6, m = bm & 63;
  float acc = 0.f;
#pragma unroll
  for (int ks = 0; ks < 8; ks++)
    acc += sump[((size_t)(ks * B_ + b) * M_ + m) * D_ + c];
  comb[((size_t)b * M_ + m) * (2 * D_) + D_ + c] = bf16_of(acc);
}

// ---------------- cell GEMM: split-K partials ----------------
__global__ __launch_bounds__(256) void k_cell_part(
    const unsigned short* __restrict__ comb, const unsigned short* __restrict__ cWb,
    float* __restrict__ cellp) {
  const int nt = blockIdx.x, mt = blockIdx.y, ks = blockIdx.z;
  f32x4 acc[4];
  gemm_core(comb + ks * 512, cWb + ks * 512, 2 * D_, 512, mt * 64, nt * 64, acc);
  const int tid = threadIdx.x, w = tid >> 6, l = tid & 63;
#pragma unroll
  for (int n = 0; n < 4; n++) {
#pragma unroll
    for (int r = 0; r < 4; r++) {
      int m = mt * 64 + w * 16 + (l >> 4) * 4 + r;
      int c = nt * 64 + n * 16 + (l & 15);
      cellp[((size_t)ks * (B_ * M_) + m) * (2 * D_) + c] = acc[n][r];
    }
  }
}

// ---------------- final gating (sums 4 cell partials + bias) ----------------
__global__ void k_newmem(const float* __restrict__ cellp,
                         const float* __restrict__ cb,
                         const float* __restrict__ memout,
                         float* __restrict__ out2) {
  int i = blockIdx.x * blockDim.x + threadIdx.x;
  if (i >= B_ * M_ * D_) return;
  int r = i >> 10, d = i & 1023;
  float gsum = cb[d], csum = cb[D_ + d];
#pragma unroll
  for (int ks = 0; ks < 4; ks++) {
    gsum += cellp[((size_t)ks * (B_ * M_) + r) * (2 * D_) + d];
    csum += cellp[((size_t)ks * (B_ * M_) + r) * (2 * D_) + D_ + d];
  }
  float sg = 1.f / (1.f + __expf(-gsum));
  float sc = 1.f / (1.f + __expf(-csum));
  out2[i] = memout[i] * sg + (1.f - sg) * (csum * sc);
}

// ---------------- launch ----------------
extern "C" void kernel_launch(void* const* d_in, const int* in_sizes, int n_in,
                              void* d_out, int out_size, void* d_ws, size_t ws_size,
                              hipStream_t stream) {
  const float* tokens = (const float*)d_in[0];
  const float* memory = (const float*)d_in[1];
  const float* Wq = (const float*)d_in[2];
  const float* bq = (const float*)d_in[3];
  const float* Wk = (const float*)d_in[4];
  const float* bk = (const float*)d_in[5];
  const float* Wv = (const float*)d_in[6];
  const float* bv = (const float*)d_in[7];
  const float* Wo = (const float*)d_in[8];
  const float* bo = (const float*)d_in[9];
  const float* pool_q = (const float*)d_in[10];
  const float* cell_W = (const float*)d_in[11];
  const float* cell_b = (const float*)d_in[12];

  size_t off = 0;
  auto alloc = [&](size_t bytes) -> void* {
    void* p = (char*)d_ws + off;
    off += (bytes + 255) & ~(size_t)255;
    return p;
  };
  unsigned short* xb    = (unsigned short*)alloc((size_t)BT_ * D_ * 2);
  unsigned short* Wqkvb = (unsigned short*)alloc((size_t)3 * D_ * D_ * 2);
  unsigned short* Wob   = (unsigned short*)alloc((size_t)D_ * D_ * 2);
  unsigned short* cWb   = (unsigned short*)alloc((size_t)(2 * D_) * (2 * D_) * 2);
  unsigned short* pqb   = (unsigned short*)alloc((size_t)M_ * D_ * 2);
  unsigned short* qg    = (unsigned short*)alloc((size_t)B_ * H_ * T_ * HD_ * 2);
  unsigned short* kg    = (unsigned short*)alloc((size_t)B_ * H_ * T_ * HD_ * 2);
  unsigned short* vTg   = (unsigned short*)alloc((size_t)B_ * H_ * HD_ * T_ * 2);
  unsigned short* ctxb  = (unsigned short*)alloc((size_t)BT_ * D_ * 2);
  unsigned short* tokb  = (unsigned short*)alloc((size_t)B_ * S_ * D_ * 2);
  unsigned short* tokTb = (unsigned short*)alloc((size_t)B_ * D_ * S_ * 2);
  float*          memout= (float*)alloc((size_t)B_ * M_ * D_ * 4);
  unsigned short* comb  = (unsigned short*)alloc((size_t)B_ * M_ * 2 * D_ * 2);
  unsigned short* pwt   = (unsigned short*)alloc((size_t)B_ * M_ * S_ * 2);
  float*          pscp  = (float*)alloc((size_t)4 * B_ * M_ * S_ * 4);
  float*          sump  = (float*)alloc((size_t)8 * B_ * M_ * D_ * 4);
  float*          cellp = (float*)alloc((size_t)4 * B_ * M_ * 2 * D_ * 4);

  float* out_tok = (float*)d_out;
  float* out_mem = out_tok + (size_t)B_ * S_ * D_;

  k_build_x<<<2048, 256, 0, stream>>>(tokens, memory, xb);
  k_cast_all<<<4096, 256, 0, stream>>>(Wq, Wk, Wv, Wo, cell_W, pool_q,
                                       Wqkvb, Wob, cWb, pqb);

  k_qkv<<<dim3(24, 33), 256, 0, stream>>>(xb, Wqkvb, bq, bk, bv, qg, kg, vTg);
  k_attn<<<544, 256, 0, stream>>>(qg, kg, vTg, ctxb);
  k_out<<<dim3(8, 33), 256, 0, stream>>>(ctxb, Wob, bo, tokens, memory, out_tok,
                                         tokb, tokTb, memout, comb);
  k_pscore_part<<<dim3(32, 4, 2), 256, 0, stream>>>(pqb, tokb, pscp);
  k_psoftmax<<<B_ * M_, 256, 0, stream>>>(pscp, pwt);
  k_summary_part<<<dim3(16, 8, 2), 256, 0, stream>>>(pwt, tokTb, sump);
  k_sumcomb<<<512, 256, 0, stream>>>(sump, comb);
  k_cell_part<<<dim3(32, 2, 4), 256, 0, stream>>>(comb, cWb, cellp);
  k_newmem<<<512, 256, 0, stream>>>(cellp, cell_b, memout, out_mem);
}

// Round 5
// 240.543 us; speedup vs baseline: 1.4439x; 1.2334x over previous
//
#include <hip/hip_runtime.h>
#include <hip/hip_bf16.h>

#define B_  2
#define S_  2048
#define M_  64
#define D_  1024
#define T_  2112      // M_ + S_
#define H_  16
#define HD_ 64
#define BT_ (B_*T_)   // 4224
#define NEGBIG (-1e9f)
#define LOG2E 1.44269504f

typedef float f32x4  __attribute__((ext_vector_type(4)));
typedef short short8 __attribute__((ext_vector_type(8)));
typedef __bf16 bf16x8 __attribute__((ext_vector_type(8)));

static __device__ __forceinline__ unsigned short bf16_of(float f) {
  __hip_bfloat16 h = __float2bfloat16(f);
  return __builtin_bit_cast(unsigned short, h);
}

static __device__ __forceinline__ f32x4 mfma_bf16(short8 a, short8 b, f32x4 c) {
  return __builtin_amdgcn_mfma_f32_16x16x32_bf16(
      __builtin_bit_cast(bf16x8, a), __builtin_bit_cast(bf16x8, b), c, 0, 0, 0);
}

// async global->LDS, 16B per lane; lds base must be wave-uniform (lane adds l*16).
static __device__ __forceinline__ void gload16(const void* g, void* lds) {
  __builtin_amdgcn_global_load_lds(
      (const __attribute__((address_space(1))) unsigned int*)g,
      (__attribute__((address_space(3))) unsigned int*)lds, 16, 0, 0);
}

// ---------------- cast / concat kernels ----------------

__global__ void k_build_x(const float* __restrict__ tokens,
                          const float* __restrict__ memory,
                          unsigned short* __restrict__ xb) {
  for (int i = blockIdx.x * blockDim.x + threadIdx.x; i < BT_ * D_;
       i += gridDim.x * blockDim.x) {
    int b = i / (T_ * D_);
    int rem = i - b * (T_ * D_);
    int t = rem / D_;
    int d = rem - t * D_;
    float v = (t < M_) ? memory[((size_t)b * M_ + t) * D_ + d]
                       : tokens[((size_t)b * S_ + (t - M_)) * D_ + d];
    xb[i] = bf16_of(v);
  }
}

// casts: Wq,Wk,Wv -> contiguous Wqkvb (3x1M), Wo (1M), cell_W (4M), pool_q (64K scaled)
__global__ void k_cast_all(const float* __restrict__ Wq, const float* __restrict__ Wk,
                           const float* __restrict__ Wv, const float* __restrict__ Wo,
                           const float* __restrict__ cW, const float* __restrict__ pq,
                           unsigned short* __restrict__ Wqkvb, unsigned short* __restrict__ Wob,
                           unsigned short* __restrict__ cWb, unsigned short* __restrict__ pqb) {
  const int NW = D_ * D_;            // 1M
  const int NC = 4 * D_ * D_;        // 4M
  const int NP = M_ * D_;            // 64K
  const int total = 4 * NW + NC + NP;
  for (int i = blockIdx.x * blockDim.x + threadIdx.x; i < total;
       i += gridDim.x * blockDim.x) {
    if (i < 3 * NW) {
      int which = i >> 20, j = i & (NW - 1);
      const float* s = (which == 0) ? Wq : (which == 1) ? Wk : Wv;
      Wqkvb[i] = bf16_of(s[j]);
    } else if (i < 4 * NW) {
      int j = i - 3 * NW;
      Wob[j] = bf16_of(Wo[j]);
    } else if (i < 4 * NW + NC) {
      int j = i - 4 * NW;
      cWb[j] = bf16_of(cW[j]);
    } else {
      int j = i - 4 * NW - NC;
      pqb[j] = bf16_of(pq[j] * 0.03125f * LOG2E);   // D^-0.5, exp2-domain
    }
  }
}

// ---------------- 128x128 GEMM core (m97 structure) ----------------
__device__ __forceinline__ void gemm128_core(const unsigned short* __restrict__ A,
                                             const unsigned short* __restrict__ BT,
                                             int K, int m0, int n0,
                                             f32x4 acc[4][4]) {
  __shared__ __align__(16) unsigned short As[128][32];
  __shared__ __align__(16) unsigned short Bs[128][32];
  const int tid = threadIdx.x;
  const int w = tid >> 6, l = tid & 63;
  const int wr = w >> 1, wc = w & 1;
  const int srow = l >> 2;
  const int scol = (l & 3) * 8;
  f32x4 z; z[0] = z[1] = z[2] = z[3] = 0.f;
#pragma unroll
  for (int i = 0; i < 4; i++)
#pragma unroll
    for (int j = 0; j < 4; j++) acc[i][j] = z;

  for (int k0 = 0; k0 < K; k0 += 32) {
    __syncthreads();
#pragma unroll
    for (int c = 0; c < 2; c++) {
      int rbase = w * 32 + c * 16;
      gload16(&A[(size_t)(m0 + rbase + srow) * K + k0 + scol], &As[rbase][0]);
      gload16(&BT[(size_t)(n0 + rbase + srow) * K + k0 + scol], &Bs[rbase][0]);
    }
    __syncthreads();
    short8 a[4], b[4];
#pragma unroll
    for (int i = 0; i < 4; i++)
      a[i] = *(const short8*)&As[wr * 64 + i * 16 + (l & 15)][(l >> 4) * 8];
#pragma unroll
    for (int j = 0; j < 4; j++)
      b[j] = *(const short8*)&Bs[wc * 64 + j * 16 + (l & 15)][(l >> 4) * 8];
#pragma unroll
    for (int i = 0; i < 4; i++)
#pragma unroll
      for (int j = 0; j < 4; j++)
        acc[i][j] = mfma_bf16(a[i], b[j], acc[i][j]);
  }
}

// ---------------- small 64x64 GEMM core (partial-K capable) ----------------
__device__ __forceinline__ void gemm_core(const unsigned short* __restrict__ A,
                                          const unsigned short* __restrict__ BT,
                                          int ldk, int Klen, int m0, int n0,
                                          f32x4 acc[4]) {
  __shared__ __align__(16) unsigned short As[64][40];
  __shared__ __align__(16) unsigned short Bs[64][40];
  const int tid = threadIdx.x;
  const int w = tid >> 6, l = tid & 63;
  const int sr = tid >> 2, sc = (tid & 3) * 8;
  f32x4 z; z[0] = z[1] = z[2] = z[3] = 0.f;
  acc[0] = acc[1] = acc[2] = acc[3] = z;
  for (int k0 = 0; k0 < Klen; k0 += 32) {
    __syncthreads();
    *(short8*)&As[sr][sc] = *(const short8*)&A[(size_t)(m0 + sr) * ldk + k0 + sc];
    *(short8*)&Bs[sr][sc] = *(const short8*)&BT[(size_t)(n0 + sr) * ldk + k0 + sc];
    __syncthreads();
    short8 a = *(const short8*)&As[w * 16 + (l & 15)][(l >> 4) * 8];
#pragma unroll
    for (int n = 0; n < 4; n++) {
      short8 b = *(const short8*)&Bs[n * 16 + (l & 15)][(l >> 4) * 8];
      acc[n] = mfma_bf16(a, b, acc[n]);
    }
  }
}

// ---------------- fused QKV projection (128-tile, single launch) ----------------
// grid: x = n-tile (24: 8 per Q/K/V), y = m-tile (33). which = bx>>3.
__global__ __launch_bounds__(256) void k_qkv(
    const unsigned short* __restrict__ xb, const unsigned short* __restrict__ Wqkvb,
    const float* __restrict__ bq, const float* __restrict__ bk,
    const float* __restrict__ bv, unsigned short* __restrict__ qg,
    unsigned short* __restrict__ kg, unsigned short* __restrict__ vTg) {
  const int which = blockIdx.x >> 3;
  const unsigned short* W = Wqkvb + (size_t)which * D_ * D_;
  const float* bias = (which == 0) ? bq : ((which == 1) ? bk : bv);
  f32x4 acc[4][4];
  const int m0 = blockIdx.y * 128, n0 = (blockIdx.x & 7) * 128;
  gemm128_core(xb, W, D_, m0, n0, acc);
  const int tid = threadIdx.x, w = tid >> 6, l = tid & 63;
  const int wr = w >> 1, wc = w & 1;
#pragma unroll
  for (int i = 0; i < 4; i++) {
#pragma unroll
    for (int j = 0; j < 4; j++) {
#pragma unroll
      for (int r = 0; r < 4; r++) {
        int m = m0 + wr * 64 + i * 16 + (l >> 4) * 4 + r;
        int c = n0 + wc * 64 + j * 16 + (l & 15);
        int b = m / T_, t = m - b * T_;
        int h = c >> 6, dh = c & 63;
        int bh = b * H_ + h;
        float v = acc[i][j][r] + bias[c];
        if (which == 0)
          qg[((size_t)bh * T_ + t) * HD_ + dh] = bf16_of(v * 0.125f * LOG2E);
        else if (which == 1)
          kg[((size_t)bh * T_ + t) * HD_ + dh] = bf16_of(v);
        else
          vTg[((size_t)bh * HD_ + dh) * T_ + t] = bf16_of(v);
      }
    }
  }
}

// ---------------- fused attention ----------------
// grid: 1056 blocks.  id = 8*((bh/8)*33 + (32-qt)) + bh%8  (bh-group -> XCD via
// id%8 round-robin; heavy q-tiles first).  Block = 4 waves, 64 q-rows; wave w
// owns rows [qt*64 + w*16, +16).  K/V dbuf-staged via global_load_lds with
// XOR-swizzled source, swizzled ds_read.  Online softmax in exp2 domain with
// per-lane lazy row-sum + defer-max (THR=8).
__global__ __launch_bounds__(256) void k_attn(
    const unsigned short* __restrict__ qg, const unsigned short* __restrict__ kg,
    const unsigned short* __restrict__ vTg, unsigned short* __restrict__ ctx) {
  const int id = blockIdx.x;
  const int xcd = id & 7;
  const int rem = id >> 3;
  const int g = rem / 33, qtr = rem - g * 33;
  const int qt = 32 - qtr;
  const int bh = g * 8 + xcd;
  const int tid = threadIdx.x, w = tid >> 6, l = tid & 63;
  const int lr = l & 15, lg = l >> 4;
  __shared__ __align__(16) unsigned short Ks[2][64][64];
  __shared__ __align__(16) unsigned short Vs[2][64][64];
  __shared__ __align__(16) unsigned short Ps[4][16][72];

  const unsigned short* qb = qg + (size_t)bh * T_ * HD_;
  const unsigned short* kb = kg + (size_t)bh * T_ * HD_;
  const unsigned short* vb = vTg + (size_t)bh * HD_ * T_;

  // q fragments for this wave's 16 rows
  short8 aq[2];
  const int qrow = qt * 64 + w * 16 + lr;
#pragma unroll
  for (int st = 0; st < 2; st++)
    aq[st] = *(const short8*)&qb[(size_t)qrow * HD_ + st * 32 + lg * 8];

  f32x4 zz; zz[0] = zz[1] = zz[2] = zz[3] = 0.f;
  f32x4 o[4];
  o[0] = o[1] = o[2] = o[3] = zz;
  float mrun[4], lrun[4];
#pragma unroll
  for (int r = 0; r < 4; r++) { mrun[r] = -1e30f; lrun[r] = 0.f; }

  const int nkt = (qt == 0) ? 33 : qt + 1;

  // stage 64x64 K and V tiles (col kb2..+63) into buffer buf, swizzled source
  auto stage = [&](int buf, int kb2) {
#pragma unroll
    for (int i = 0; i < 2; i++) {
      int rr = w * 16 + i * 8 + (l >> 3);            // row within 64-tile
      int swz = ((l & 7) ^ (rr & 7)) * 8;            // swizzled 16B-unit (elems)
      gload16(&kb[(size_t)(kb2 + rr) * HD_ + swz], &Ks[buf][w * 16 + i * 8][0]);
      gload16(&vb[(size_t)rr * T_ + kb2 + swz], &Vs[buf][w * 16 + i * 8][0]);
    }
  };

  stage(0, 0);
  __syncthreads();
  int cur = 0;

  for (int j = 0; j < nkt; j++) {
    const int kbase = j * 64;
    if (j + 1 < nkt) stage(cur ^ 1, kbase + 64);     // async prefetch next tile

    // K fragments from LDS (swizzled read)
    short8 bkf[2][4];
#pragma unroll
    for (int n = 0; n < 4; n++) {
      int row = n * 16 + lr;
      int sw = lr & 7;
#pragma unroll
      for (int st = 0; st < 2; st++)
        bkf[st][n] = *(const short8*)&Ks[cur][row][((st * 4 + lg) ^ sw) * 8];
    }
    f32x4 s[4];
    s[0] = s[1] = s[2] = s[3] = zz;
#pragma unroll
    for (int st = 0; st < 2; st++)
#pragma unroll
      for (int n = 0; n < 4; n++)
        s[n] = mfma_bf16(aq[st], bkf[st][n], s[n]);

    // causal mask on diagonal tile (qt==0 is all memory rows: no mask)
    if (qt > 0 && j == qt) {
#pragma unroll
      for (int n = 0; n < 4; n++)
#pragma unroll
        for (int r = 0; r < 4; r++) {
          int t1l = w * 16 + lg * 4 + r;   // local q (within 64)
          int t2l = n * 16 + lr;           // local k
          if (t2l > t1l) s[n][r] = NEGBIG;
        }
    }
    // row max (across the 16 lr lanes)
    float pm[4];
#pragma unroll
    for (int r = 0; r < 4; r++) {
      pm[r] = fmaxf(fmaxf(s[0][r], s[1][r]), fmaxf(s[2][r], s[3][r]));
#pragma unroll
      for (int mk = 1; mk < 16; mk <<= 1) pm[r] = fmaxf(pm[r], __shfl_xor(pm[r], mk));
    }
    // defer-max: only rescale when some row's max grew by > 8 (exp2 domain)
    bool need = false;
#pragma unroll
    for (int r = 0; r < 4; r++) need = need || (pm[r] > mrun[r] + 8.f);
    if (__any(need)) {
#pragma unroll
      for (int r = 0; r < 4; r++) {
        float mn = fmaxf(mrun[r], pm[r]);
        float fac = exp2f(mrun[r] - mn);
        mrun[r] = mn;
        lrun[r] *= fac;
#pragma unroll
        for (int n = 0; n < 4; n++) o[n][r] *= fac;
      }
    }
    // P = exp2(S - m); per-lane partial row-sum (reduced once in epilogue)
#pragma unroll
    for (int n = 0; n < 4; n++)
#pragma unroll
      for (int r = 0; r < 4; r++) {
        float p = exp2f(s[n][r] - mrun[r]);
        lrun[r] += p;
        Ps[w][lg * 4 + r][n * 16 + lr] = bf16_of(p);
      }

    // V fragments from LDS (swizzled read), then PV
    short8 bvf[2][4];
#pragma unroll
    for (int n = 0; n < 4; n++) {
      int row = n * 16 + lr;                          // dh
      int sw = lr & 7;
#pragma unroll
      for (int st = 0; st < 2; st++)
        bvf[st][n] = *(const short8*)&Vs[cur][row][((st * 4 + lg) ^ sw) * 8];
    }
    short8 ap[2];
#pragma unroll
    for (int st = 0; st < 2; st++)
      ap[st] = *(const short8*)&Ps[w][lr][st * 32 + lg * 8];
#pragma unroll
    for (int st = 0; st < 2; st++)
#pragma unroll
      for (int n = 0; n < 4; n++)
        o[n] = mfma_bf16(ap[st], bvf[st][n], o[n]);

    __syncthreads();   // drains prefetch (vmcnt) + guards buffer reuse
    cur ^= 1;
  }
  // epilogue: reduce per-lane lrun partials across the 16 lanes of each row
#pragma unroll
  for (int r = 0; r < 4; r++)
#pragma unroll
    for (int mk = 1; mk < 16; mk <<= 1) lrun[r] += __shfl_xor(lrun[r], mk);

  const int b = bh >> 4, h = bh & 15;
#pragma unroll
  for (int n = 0; n < 4; n++)
#pragma unroll
    for (int r = 0; r < 4; r++) {
      int tq = qt * 64 + w * 16 + lg * 4 + r;
      float val = o[n][r] / lrun[r];
      ctx[((size_t)(b * T_ + tq)) * D_ + h * HD_ + n * 16 + lr] = bf16_of(val);
    }
}

// ---------------- output projection + residual + splits (128-tile) ----------------
__global__ __launch_bounds__(256) void k_out(
    const unsigned short* __restrict__ ctxb, const unsigned short* __restrict__ Wob,
    const float* __restrict__ bo, const float* __restrict__ tokens,
    const float* __restrict__ memory, float* __restrict__ out_tok,
    unsigned short* __restrict__ tokb, unsigned short* __restrict__ tokTb,
    float* __restrict__ memout, unsigned short* __restrict__ comb) {
  f32x4 acc[4][4];
  const int m0 = blockIdx.y * 128, n0 = blockIdx.x * 128;
  gemm128_core(ctxb, Wob, D_, m0, n0, acc);
  const int tid = threadIdx.x, w = tid >> 6, l = tid & 63;
  const int wr = w >> 1, wc = w & 1;
#pragma unroll
  for (int i = 0; i < 4; i++) {
#pragma unroll
    for (int j = 0; j < 4; j++) {
#pragma unroll
      for (int r = 0; r < 4; r++) {
        int m = m0 + wr * 64 + i * 16 + (l >> 4) * 4 + r;
        int c = n0 + wc * 64 + j * 16 + (l & 15);
        int b = m / T_, t = m - b * T_;
        float xo = (t < M_) ? memory[((size_t)b * M_ + t) * D_ + c]
                            : tokens[((size_t)b * S_ + (t - M_)) * D_ + c];
        float val = acc[i][j][r] + bo[c] + xo;
        if (t < M_) {
          memout[((size_t)b * M_ + t) * D_ + c] = val;
          comb[((size_t)b * M_ + t) * (2 * D_) + c] = bf16_of(val);
        } else {
          size_t ti = (size_t)b * S_ + (t - M_);
          out_tok[ti * D_ + c] = val;
          tokb[ti * D_ + c] = bf16_of(val);
          tokTb[((size_t)b * D_ + c) * S_ + (t - M_)] = bf16_of(val);
        }
      }
    }
  }
}

// ---------------- pool scores: split-K partials ----------------
__global__ __launch_bounds__(256) void k_pscore_part(
    const unsigned short* __restrict__ pqb, const unsigned short* __restrict__ tokb,
    float* __restrict__ pscp) {
  const int stile = blockIdx.x, ks = blockIdx.y, b = blockIdx.z;
  f32x4 acc[4];
  gemm_core(pqb + ks * 256, tokb + (size_t)b * S_ * D_ + ks * 256, D_, 256,
            0, stile * 64, acc);
  const int tid = threadIdx.x, w = tid >> 6, l = tid & 63;
  float* dst = pscp + ((size_t)(ks * B_ + b) * M_) * S_;
#pragma unroll
  for (int n = 0; n < 4; n++) {
#pragma unroll
    for (int r = 0; r < 4; r++) {
      int m = w * 16 + (l >> 4) * 4 + r;
      int s = stile * 64 + n * 16 + (l & 15);
      dst[(size_t)m * S_ + s] = acc[n][r];
    }
  }
}

// ---------------- pool softmax (sums 4 partials; exp2 domain) ----------------
__global__ __launch_bounds__(256) void k_psoftmax(const float* __restrict__ pscp,
                                                  unsigned short* __restrict__ pw) {
  const int row = blockIdx.x;          // b*64 + m
  const int b = row >> 6, m = row & 63;
  const int tid = threadIdx.x;
  float v[8];
  float mx = -1e30f;
#pragma unroll
  for (int i = 0; i < 8; i++) {
    int s = tid + i * 256;
    float acc = 0.f;
#pragma unroll
    for (int ks = 0; ks < 4; ks++)
      acc += pscp[((size_t)(ks * B_ + b) * M_ + m) * S_ + s];
    v[i] = acc;
    mx = fmaxf(mx, acc);
  }
#pragma unroll
  for (int off = 1; off < 64; off <<= 1) mx = fmaxf(mx, __shfl_xor(mx, off));
  __shared__ float rm[4], rs[4];
  if ((tid & 63) == 0) rm[tid >> 6] = mx;
  __syncthreads();
  mx = fmaxf(fmaxf(rm[0], rm[1]), fmaxf(rm[2], rm[3]));
  float sum = 0.f;
#pragma unroll
  for (int i = 0; i < 8; i++) {
    v[i] = exp2f(v[i] - mx);
    sum += v[i];
  }
#pragma unroll
  for (int off = 1; off < 64; off <<= 1) sum += __shfl_xor(sum, off);
  if ((tid & 63) == 0) rs[tid >> 6] = sum;
  __syncthreads();
  float inv = 1.f / (rs[0] + rs[1] + rs[2] + rs[3]);
#pragma unroll
  for (int i = 0; i < 8; i++)
    pw[(size_t)row * S_ + tid + i * 256] = bf16_of(v[i] * inv);
}

// ---------------- summary: split-K partials ----------------
__global__ __launch_bounds__(256) void k_summary_part(
    const unsigned short* __restrict__ pw, const unsigned short* __restrict__ tokTb,
    float* __restrict__ sump) {
  const int nt = blockIdx.x, ks = blockIdx.y, b = blockIdx.z;
  f32x4 acc[4];
  gemm_core(pw + (size_t)b * M_ * S_ + ks * 256,
            tokTb + (size_t)b * D_ * S_ + ks * 256, S_, 256, 0, nt * 64, acc);
  const int tid = threadIdx.x, w = tid >> 6, l = tid & 63;
  float* dst = sump + ((size_t)(ks * B_ + b) * M_) * D_;
#pragma unroll
  for (int n = 0; n < 4; n++) {
#pragma unroll
    for (int r = 0; r < 4; r++) {
      int m = w * 16 + (l >> 4) * 4 + r;
      int c = nt * 64 + n * 16 + (l & 15);
      dst[(size_t)m * D_ + c] = acc[n][r];
    }
  }
}

// combine summary partials -> comb[:, D_:]
__global__ void k_sumcomb(const float* __restrict__ sump,
                          unsigned short* __restrict__ comb) {
  int i = blockIdx.x * blockDim.x + threadIdx.x;
  if (i >= B_ * M_ * D_) return;
  int bm = i >> 10, c = i & 1023;
  int b = bm >> 6, m = bm & 63;
  float acc = 0.f;
#pragma unroll
  for (int ks = 0; ks < 8; ks++)
    acc += sump[((size_t)(ks * B_ + b) * M_ + m) * D_ + c];
  comb[((size_t)b * M_ + m) * (2 * D_) + D_ + c] = bf16_of(acc);
}

// ---------------- cell GEMM: split-K partials ----------------
__global__ __launch_bounds__(256) void k_cell_part(
    const unsigned short* __restrict__ comb, const unsigned short* __restrict__ cWb,
    float* __restrict__ cellp) {
  const int nt = blockIdx.x, mt = blockIdx.y, ks = blockIdx.z;
  f32x4 acc[4];
  gemm_core(comb + ks * 512, cWb + ks * 512, 2 * D_, 512, mt * 64, nt * 64, acc);
  const int tid = threadIdx.x, w = tid >> 6, l = tid & 63;
#pragma unroll
  for (int n = 0; n < 4; n++) {
#pragma unroll
    for (int r = 0; r < 4; r++) {
      int m = mt * 64 + w * 16 + (l >> 4) * 4 + r;
      int c = nt * 64 + n * 16 + (l & 15);
      cellp[((size_t)ks * (B_ * M_) + m) * (2 * D_) + c] = acc[n][r];
    }
  }
}

// ---------------- final gating (sums 4 cell partials + bias) ----------------
__global__ void k_newmem(const float* __restrict__ cellp,
                         const float* __restrict__ cb,
                         const float* __restrict__ memout,
                         float* __restrict__ out2) {
  int i = blockIdx.x * blockDim.x + threadIdx.x;
  if (i >= B_ * M_ * D_) return;
  int r = i >> 10, d = i & 1023;
  float gsum = cb[d], csum = cb[D_ + d];
#pragma unroll
  for (int ks = 0; ks < 4; ks++) {
    gsum += cellp[((size_t)ks * (B_ * M_) + r) * (2 * D_) + d];
    csum += cellp[((size_t)ks * (B_ * M_) + r) * (2 * D_) + D_ + d];
  }
  float sg = 1.f / (1.f + __expf(-gsum));
  float sc = 1.f / (1.f + __expf(-csum));
  out2[i] = memout[i] * sg + (1.f - sg) * (csum * sc);
}

// ---------------- launch ----------------
extern "C" void kernel_launch(void* const* d_in, const int* in_sizes, int n_in,
                              void* d_out, int out_size, void* d_ws, size_t ws_size,
                              hipStream_t stream) {
  const float* tokens = (const float*)d_in[0];
  const float* memory = (const float*)d_in[1];
  const float* Wq = (const float*)d_in[2];
  const float* bq = (const float*)d_in[3];
  const float* Wk = (const float*)d_in[4];
  const float* bk = (const float*)d_in[5];
  const float* Wv = (const float*)d_in[6];
  const float* bv = (const float*)d_in[7];
  const float* Wo = (const float*)d_in[8];
  const float* bo = (const float*)d_in[9];
  const float* pool_q = (const float*)d_in[10];
  const float* cell_W = (const float*)d_in[11];
  const float* cell_b = (const float*)d_in[12];

  size_t off = 0;
  auto alloc = [&](size_t bytes) -> void* {
    void* p = (char*)d_ws + off;
    off += (bytes + 255) & ~(size_t)255;
    return p;
  };
  unsigned short* xb    = (unsigned short*)alloc((size_t)BT_ * D_ * 2);
  unsigned short* Wqkvb = (unsigned short*)alloc((size_t)3 * D_ * D_ * 2);
  unsigned short* Wob   = (unsigned short*)alloc((size_t)D_ * D_ * 2);
  unsigned short* cWb   = (unsigned short*)alloc((size_t)(2 * D_) * (2 * D_) * 2);
  unsigned short* pqb   = (unsigned short*)alloc((size_t)M_ * D_ * 2);
  unsigned short* qg    = (unsigned short*)alloc((size_t)B_ * H_ * T_ * HD_ * 2);
  unsigned short* kg    = (unsigned short*)alloc((size_t)B_ * H_ * T_ * HD_ * 2);
  unsigned short* vTg   = (unsigned short*)alloc((size_t)B_ * H_ * HD_ * T_ * 2);
  unsigned short* ctxb  = (unsigned short*)alloc((size_t)BT_ * D_ * 2);
  unsigned short* tokb  = (unsigned short*)alloc((size_t)B_ * S_ * D_ * 2);
  unsigned short* tokTb = (unsigned short*)alloc((size_t)B_ * D_ * S_ * 2);
  float*          memout= (float*)alloc((size_t)B_ * M_ * D_ * 4);
  unsigned short* comb  = (unsigned short*)alloc((size_t)B_ * M_ * 2 * D_ * 2);
  unsigned short* pwt   = (unsigned short*)alloc((size_t)B_ * M_ * S_ * 2);
  float*          pscp  = (float*)alloc((size_t)4 * B_ * M_ * S_ * 4);
  float*          sump  = (float*)alloc((size_t)8 * B_ * M_ * D_ * 4);
  float*          cellp = (float*)alloc((size_t)4 * B_ * M_ * 2 * D_ * 4);

  float* out_tok = (float*)d_out;
  float* out_mem = out_tok + (size_t)B_ * S_ * D_;

  k_build_x<<<2048, 256, 0, stream>>>(tokens, memory, xb);
  k_cast_all<<<4096, 256, 0, stream>>>(Wq, Wk, Wv, Wo, cell_W, pool_q,
                                       Wqkvb, Wob, cWb, pqb);

  k_qkv<<<dim3(24, 33), 256, 0, stream>>>(xb, Wqkvb, bq, bk, bv, qg, kg, vTg);
  k_attn<<<1056, 256, 0, stream>>>(qg, kg, vTg, ctxb);
  k_out<<<dim3(8, 33), 256, 0, stream>>>(ctxb, Wob, bo, tokens, memory, out_tok,
                                         tokb, tokTb, memout, comb);
  k_pscore_part<<<dim3(32, 4, 2), 256, 0, stream>>>(pqb, tokb, pscp);
  k_psoftmax<<<B_ * M_, 256, 0, stream>>>(pscp, pwt);
  k_summary_part<<<dim3(16, 8, 2), 256, 0, stream>>>(pwt, tokTb, sump);
  k_sumcomb<<<512, 256, 0, stream>>>(sump, comb);
  k_cell_part<<<dim3(32, 2, 4), 256, 0, stream>>>(comb, cWb, cellp);
  k_newmem<<<512, 256, 0, stream>>>(cellp, cell_b, memout, out_mem);
}

// Round 7
// 219.450 us; speedup vs baseline: 1.5827x; 1.0961x over previous
//
#include <hip/hip_runtime.h>
#include <hip/hip_bf16.h>

#define B_  2
#define S_  2048
#define M_  64
#define D_  1024
#define T_  2112      // M_ + S_
#define H_  16
#define HD_ 64
#define BT_ (B_*T_)   // 4224
#define NEGBIG (-1e9f)
#define LOG2E 1.44269504f

typedef float f32x4  __attribute__((ext_vector_type(4)));
typedef short short8 __attribute__((ext_vector_type(8)));
typedef unsigned short u16x4 __attribute__((ext_vector_type(4)));
typedef __bf16 bf16x8 __attribute__((ext_vector_type(8)));

static __device__ __forceinline__ unsigned short bf16_of(float f) {
  __hip_bfloat16 h = __float2bfloat16(f);
  return __builtin_bit_cast(unsigned short, h);
}

static __device__ __forceinline__ f32x4 mfma_bf16(short8 a, short8 b, f32x4 c) {
  return __builtin_amdgcn_mfma_f32_16x16x32_bf16(
      __builtin_bit_cast(bf16x8, a), __builtin_bit_cast(bf16x8, b), c, 0, 0, 0);
}

// async global->LDS, 16B per lane; lds base must be wave-uniform (lane adds l*16).
static __device__ __forceinline__ void gload16(const void* g, void* lds) {
  __builtin_amdgcn_global_load_lds(
      (const __attribute__((address_space(1))) unsigned int*)g,
      (__attribute__((address_space(3))) unsigned int*)lds, 16, 0, 0);
}

// ---------------- cast / concat kernels ----------------

__global__ void k_build_x(const float* __restrict__ tokens,
                          const float* __restrict__ memory,
                          unsigned short* __restrict__ xb) {
  for (int i = blockIdx.x * blockDim.x + threadIdx.x; i < BT_ * D_;
       i += gridDim.x * blockDim.x) {
    int b = i / (T_ * D_);
    int rem = i - b * (T_ * D_);
    int t = rem / D_;
    int d = rem - t * D_;
    float v = (t < M_) ? memory[((size_t)b * M_ + t) * D_ + d]
                       : tokens[((size_t)b * S_ + (t - M_)) * D_ + d];
    xb[i] = bf16_of(v);
  }
}

// casts: Wq,Wk,Wv -> contiguous Wqkvb (3x1M), Wo (1M), cell_W (4M), pool_q (64K scaled)
__global__ void k_cast_all(const float* __restrict__ Wq, const float* __restrict__ Wk,
                           const float* __restrict__ Wv, const float* __restrict__ Wo,
                           const float* __restrict__ cW, const float* __restrict__ pq,
                           unsigned short* __restrict__ Wqkvb, unsigned short* __restrict__ Wob,
                           unsigned short* __restrict__ cWb, unsigned short* __restrict__ pqb) {
  const int NW = D_ * D_;            // 1M
  const int NC = 4 * D_ * D_;        // 4M
  const int NP = M_ * D_;            // 64K
  const int total = 4 * NW + NC + NP;
  for (int i = blockIdx.x * blockDim.x + threadIdx.x; i < total;
       i += gridDim.x * blockDim.x) {
    if (i < 3 * NW) {
      int which = i >> 20, j = i & (NW - 1);
      const float* s = (which == 0) ? Wq : (which == 1) ? Wk : Wv;
      Wqkvb[i] = bf16_of(s[j]);
    } else if (i < 4 * NW) {
      int j = i - 3 * NW;
      Wob[j] = bf16_of(Wo[j]);
    } else if (i < 4 * NW + NC) {
      int j = i - 4 * NW;
      cWb[j] = bf16_of(cW[j]);
    } else {
      int j = i - 4 * NW - NC;
      pqb[j] = bf16_of(pq[j] * 0.03125f * LOG2E);   // D^-0.5, exp2-domain
    }
  }
}

// ---------------- 128x128 GEMM core (m97 structure) ----------------
__device__ __forceinline__ void gemm128_core(const unsigned short* __restrict__ A,
                                             const unsigned short* __restrict__ BT,
                                             int K, int m0, int n0,
                                             f32x4 acc[4][4]) {
  __shared__ __align__(16) unsigned short As[128][32];
  __shared__ __align__(16) unsigned short Bs[128][32];
  const int tid = threadIdx.x;
  const int w = tid >> 6, l = tid & 63;
  const int wr = w >> 1, wc = w & 1;
  const int srow = l >> 2;
  const int scol = (l & 3) * 8;
  f32x4 z; z[0] = z[1] = z[2] = z[3] = 0.f;
#pragma unroll
  for (int i = 0; i < 4; i++)
#pragma unroll
    for (int j = 0; j < 4; j++) acc[i][j] = z;

  for (int k0 = 0; k0 < K; k0 += 32) {
    __syncthreads();
#pragma unroll
    for (int c = 0; c < 2; c++) {
      int rbase = w * 32 + c * 16;
      gload16(&A[(size_t)(m0 + rbase + srow) * K + k0 + scol], &As[rbase][0]);
      gload16(&BT[(size_t)(n0 + rbase + srow) * K + k0 + scol], &Bs[rbase][0]);
    }
    __syncthreads();
    short8 a[4], b[4];
#pragma unroll
    for (int i = 0; i < 4; i++)
      a[i] = *(const short8*)&As[wr * 64 + i * 16 + (l & 15)][(l >> 4) * 8];
#pragma unroll
    for (int j = 0; j < 4; j++)
      b[j] = *(const short8*)&Bs[wc * 64 + j * 16 + (l & 15)][(l >> 4) * 8];
#pragma unroll
    for (int i = 0; i < 4; i++)
#pragma unroll
      for (int j = 0; j < 4; j++)
        acc[i][j] = mfma_bf16(a[i], b[j], acc[i][j]);
  }
}

// ---------------- small 64x64 GEMM core (partial-K capable) ----------------
__device__ __forceinline__ void gemm_core(const unsigned short* __restrict__ A,
                                          const unsigned short* __restrict__ BT,
                                          int ldk, int Klen, int m0, int n0,
                                          f32x4 acc[4]) {
  __shared__ __align__(16) unsigned short As[64][40];
  __shared__ __align__(16) unsigned short Bs[64][40];
  const int tid = threadIdx.x;
  const int w = tid >> 6, l = tid & 63;
  const int sr = tid >> 2, sc = (tid & 3) * 8;
  f32x4 z; z[0] = z[1] = z[2] = z[3] = 0.f;
  acc[0] = acc[1] = acc[2] = acc[3] = z;
  for (int k0 = 0; k0 < Klen; k0 += 32) {
    __syncthreads();
    *(short8*)&As[sr][sc] = *(const short8*)&A[(size_t)(m0 + sr) * ldk + k0 + sc];
    *(short8*)&Bs[sr][sc] = *(const short8*)&BT[(size_t)(n0 + sr) * ldk + k0 + sc];
    __syncthreads();
    short8 a = *(const short8*)&As[w * 16 + (l & 15)][(l >> 4) * 8];
#pragma unroll
    for (int n = 0; n < 4; n++) {
      short8 b = *(const short8*)&Bs[n * 16 + (l & 15)][(l >> 4) * 8];
      acc[n] = mfma_bf16(a, b, acc[n]);
    }
  }
}

// ---------------- fused QKV projection (128-tile, single launch) ----------------
// grid: x = n-tile (24: 8 per Q/K/V), y = m-tile (33). which = bx>>3.
__global__ __launch_bounds__(256) void k_qkv(
    const unsigned short* __restrict__ xb, const unsigned short* __restrict__ Wqkvb,
    const float* __restrict__ bq, const float* __restrict__ bk,
    const float* __restrict__ bv, unsigned short* __restrict__ qg,
    unsigned short* __restrict__ kg, unsigned short* __restrict__ vTg) {
  const int which = blockIdx.x >> 3;
  const unsigned short* W = Wqkvb + (size_t)which * D_ * D_;
  const float* bias = (which == 0) ? bq : ((which == 1) ? bk : bv);
  f32x4 acc[4][4];
  const int m0 = blockIdx.y * 128, n0 = (blockIdx.x & 7) * 128;
  gemm128_core(xb, W, D_, m0, n0, acc);
  const int tid = threadIdx.x, w = tid >> 6, l = tid & 63;
  const int wr = w >> 1, wc = w & 1;
#pragma unroll
  for (int i = 0; i < 4; i++) {
#pragma unroll
    for (int j = 0; j < 4; j++) {
#pragma unroll
      for (int r = 0; r < 4; r++) {
        int m = m0 + wr * 64 + i * 16 + (l >> 4) * 4 + r;
        int c = n0 + wc * 64 + j * 16 + (l & 15);
        int b = m / T_, t = m - b * T_;
        int h = c >> 6, dh = c & 63;
        int bh = b * H_ + h;
        float v = acc[i][j][r] + bias[c];
        if (which == 0)
          qg[((size_t)bh * T_ + t) * HD_ + dh] = bf16_of(v * 0.125f * LOG2E);
        else if (which == 1)
          kg[((size_t)bh * T_ + t) * HD_ + dh] = bf16_of(v);
        else
          vTg[((size_t)bh * HD_ + dh) * T_ + t] = bf16_of(v);
      }
    }
  }
}

// ---------------- fused attention: swapped-operand QK^T, lane-local softmax ----------------
// grid: 1056 blocks.  id = 8*((bh/8)*33 + qtr) + bh%8; qt = qtr==0 ? 0 : 33-qtr
// (bh-group -> XCD, heavy tiles first INCLUDING qt=0).
// Block = 4 waves, 64 q-rows; wave w owns rows [qt*64 + w*16, +16).
// QK^T computed as mfma(K, Q) -> lane owns one q-row (ql = lane&15): row max is
// in-register + 2 shfl; P packs to 4 ds_write_b64.  mrun/lrun are lane scalars.
__global__ __launch_bounds__(256) void k_attn(
    const unsigned short* __restrict__ qg, const unsigned short* __restrict__ kg,
    const unsigned short* __restrict__ vTg, unsigned short* __restrict__ ctx) {
  const int id = blockIdx.x;
  const int xcd = id & 7;
  const int rem = id >> 3;
  const int g = rem / 33, qtr = rem - g * 33;
  const int qt = (qtr == 0) ? 0 : 33 - qtr;
  const int bh = g * 8 + xcd;
  const int tid = threadIdx.x, w = tid >> 6, l = tid & 63;
  const int lr = l & 15, lg = l >> 4;
  __shared__ __align__(16) unsigned short Ks[2][64][64];
  __shared__ __align__(16) unsigned short Vs[2][64][64];
  __shared__ __align__(16) unsigned short Ps[4][16][72];

  const unsigned short* qb = qg + (size_t)bh * T_ * HD_;
  const unsigned short* kb = kg + (size_t)bh * T_ * HD_;
  const unsigned short* vb = vTg + (size_t)bh * HD_ * T_;

  // Q B-fragment: row = lr = this wave's q-row, cols lg*8
  short8 aq[2];
  const int qrow = qt * 64 + w * 16 + lr;
#pragma unroll
  for (int st = 0; st < 2; st++)
    aq[st] = *(const short8*)&qb[(size_t)qrow * HD_ + st * 32 + lg * 8];

  f32x4 zz; zz[0] = zz[1] = zz[2] = zz[3] = 0.f;
  f32x4 o[4];
  o[0] = o[1] = o[2] = o[3] = zz;
  float mrun = -1e30f, lrun = 0.f;   // lane-scalar state for q-row (w*16+lr)

  const int nkt = (qt == 0) ? 33 : qt + 1;

  // stage 64x64 K and V tiles (col kb2..+63) into buffer buf, swizzled source
  auto stage = [&](int buf, int kb2) {
#pragma unroll
    for (int i = 0; i < 2; i++) {
      int rr = w * 16 + i * 8 + (l >> 3);            // row within 64-tile
      int swz = ((l & 7) ^ (rr & 7)) * 8;            // swizzled 16B-unit (elems)
      gload16(&kb[(size_t)(kb2 + rr) * HD_ + swz], &Ks[buf][w * 16 + i * 8][0]);
      gload16(&vb[(size_t)rr * T_ + kb2 + swz], &Vs[buf][w * 16 + i * 8][0]);
    }
  };

  stage(0, 0);
  __syncthreads();
  int cur = 0;

  for (int j = 0; j < nkt; j++) {
    const int kbase = j * 64;
    if (j + 1 < nkt) stage(cur ^ 1, kbase + 64);     // async prefetch next tile

    // K A-fragments from LDS (swizzled read); row = k-local = n*16+lr
    short8 bkf[2][4];
#pragma unroll
    for (int n = 0; n < 4; n++) {
      int row = n * 16 + lr;
      int sw = lr & 7;
#pragma unroll
      for (int st = 0; st < 2; st++)
        bkf[st][n] = *(const short8*)&Ks[cur][row][((st * 4 + lg) ^ sw) * 8];
    }
    // S^T = K * Q^T : s[n][r] = S[k = kbase + n*16 + lg*4 + r][q-row ql=lr]
    f32x4 s[4];
    s[0] = s[1] = s[2] = s[3] = zz;
    __builtin_amdgcn_s_setprio(1);
#pragma unroll
    for (int st = 0; st < 2; st++)
#pragma unroll
      for (int n = 0; n < 4; n++)
        s[n] = mfma_bf16(bkf[st][n], aq[st], s[n]);
    __builtin_amdgcn_s_setprio(0);

    // causal mask on diagonal tile (qt==0 is all memory rows: no mask)
    if (qt > 0 && j == qt) {
      const int tql = w * 16 + lr;        // local q within 64
#pragma unroll
      for (int n = 0; n < 4; n++)
#pragma unroll
        for (int r = 0; r < 4; r++) {
          int tkl = n * 16 + lg * 4 + r;  // local k within 64
          if (tkl > tql) s[n][r] = NEGBIG;
        }
    }
    // row max: in-register over this lane's 16 values + 2 shfl across lg-groups
    float pm = s[0][0];
#pragma unroll
    for (int n = 0; n < 4; n++)
#pragma unroll
      for (int r = 0; r < 4; r++) pm = fmaxf(pm, s[n][r]);
    pm = fmaxf(pm, __shfl_xor(pm, 16));
    pm = fmaxf(pm, __shfl_xor(pm, 32));

    // defer-max: rescale only when some row's max grew by > 8 (exp2 domain)
    if (__any(pm > mrun + 8.f)) {
      float mn = fmaxf(mrun, pm);
      float fac = exp2f(mrun - mn);
      mrun = mn;
      lrun *= fac;
      float fr[4];
#pragma unroll
      for (int r = 0; r < 4; r++) fr[r] = __shfl(fac, lg * 4 + r);
#pragma unroll
      for (int n = 0; n < 4; n++)
#pragma unroll
        for (int r = 0; r < 4; r++) o[n][r] *= fr[r];
    }
    // P = exp2(S - m); lane-partial row sum; pack 4 k-values -> one b64 store
#pragma unroll
    for (int n = 0; n < 4; n++) {
      u16x4 pk;
#pragma unroll
      for (int r = 0; r < 4; r++) {
        float p = exp2f(s[n][r] - mrun);
        lrun += p;
        pk[r] = bf16_of(p);
      }
      *(u16x4*)&Ps[w][lr][n * 16 + lg * 4] = pk;
    }

    // V B-fragments from LDS (swizzled read), P A-fragments, then PV
    short8 bvf[2][4];
#pragma unroll
    for (int n = 0; n < 4; n++) {
      int row = n * 16 + lr;                          // dh
      int sw = lr & 7;
#pragma unroll
      for (int st = 0; st < 2; st++)
        bvf[st][n] = *(const short8*)&Vs[cur][row][((st * 4 + lg) ^ sw) * 8];
    }
    short8 ap[2];
#pragma unroll
    for (int st = 0; st < 2; st++)
      ap[st] = *(const short8*)&Ps[w][lr][st * 32 + lg * 8];
    __builtin_amdgcn_s_setprio(1);
#pragma unroll
    for (int st = 0; st < 2; st++)
#pragma unroll
      for (int n = 0; n < 4; n++)
        o[n] = mfma_bf16(ap[st], bvf[st][n], o[n]);
    __builtin_amdgcn_s_setprio(0);

    __syncthreads();   // drains prefetch (vmcnt) + guards buffer reuse
    cur ^= 1;
  }
  // epilogue: full row sum (reduce lane partials across lg-groups), then
  // redistribute to the o-accumulator's q-mapping (q = lg*4+r)
  lrun += __shfl_xor(lrun, 16);
  lrun += __shfl_xor(lrun, 32);
  float linv[4];
#pragma unroll
  for (int r = 0; r < 4; r++) linv[r] = 1.f / __shfl(lrun, lg * 4 + r);

  const int b = bh >> 4, h = bh & 15;
#pragma unroll
  for (int n = 0; n < 4; n++)
#pragma unroll
    for (int r = 0; r < 4; r++) {
      int tq = qt * 64 + w * 16 + lg * 4 + r;
      float val = o[n][r] * linv[r];
      ctx[((size_t)(b * T_ + tq)) * D_ + h * HD_ + n * 16 + lr] = bf16_of(val);
    }
}

// ---------------- output projection + residual + splits (128-tile) ----------------
__global__ __launch_bounds__(256) void k_out(
    const unsigned short* __restrict__ ctxb, const unsigned short* __restrict__ Wob,
    const float* __restrict__ bo, const float* __restrict__ tokens,
    const float* __restrict__ memory, float* __restrict__ out_tok,
    unsigned short* __restrict__ tokb, unsigned short* __restrict__ tokTb,
    float* __restrict__ memout, unsigned short* __restrict__ comb) {
  f32x4 acc[4][4];
  const int m0 = blockIdx.y * 128, n0 = blockIdx.x * 128;
  gemm128_core(ctxb, Wob, D_, m0, n0, acc);
  const int tid = threadIdx.x, w = tid >> 6, l = tid & 63;
  const int wr = w >> 1, wc = w & 1;
#pragma unroll
  for (int i = 0; i < 4; i++) {
#pragma unroll
    for (int j = 0; j < 4; j++) {
#pragma unroll
      for (int r = 0; r < 4; r++) {
        int m = m0 + wr * 64 + i * 16 + (l >> 4) * 4 + r;
        int c = n0 + wc * 64 + j * 16 + (l & 15);
        int b = m / T_, t = m - b * T_;
        float xo = (t < M_) ? memory[((size_t)b * M_ + t) * D_ + c]
                            : tokens[((size_t)b * S_ + (t - M_)) * D_ + c];
        float val = acc[i][j][r] + bo[c] + xo;
        if (t < M_) {
          memout[((size_t)b * M_ + t) * D_ + c] = val;
          comb[((size_t)b * M_ + t) * (2 * D_) + c] = bf16_of(val);
        } else {
          size_t ti = (size_t)b * S_ + (t - M_);
          out_tok[ti * D_ + c] = val;
          tokb[ti * D_ + c] = bf16_of(val);
          tokTb[((size_t)b * D_ + c) * S_ + (t - M_)] = bf16_of(val);
        }
      }
    }
  }
}

// ---------------- pool scores: split-K partials ----------------
__global__ __launch_bounds__(256) void k_pscore_part(
    const unsigned short* __restrict__ pqb, const unsigned short* __restrict__ tokb,
    float* __restrict__ pscp) {
  const int stile = blockIdx.x, ks = blockIdx.y, b = blockIdx.z;
  f32x4 acc[4];
  gemm_core(pqb + ks * 256, tokb + (size_t)b * S_ * D_ + ks * 256, D_, 256,
            0, stile * 64, acc);
  const int tid = threadIdx.x, w = tid >> 6, l = tid & 63;
  float* dst = pscp + ((size_t)(ks * B_ + b) * M_) * S_;
#pragma unroll
  for (int n = 0; n < 4; n++) {
#pragma unroll
    for (int r = 0; r < 4; r++) {
      int m = w * 16 + (l >> 4) * 4 + r;
      int s = stile * 64 + n * 16 + (l & 15);
      dst[(size_t)m * S_ + s] = acc[n][r];
    }
  }
}

// ---------------- pool softmax (sums 4 partials; exp2 domain) ----------------
__global__ __launch_bounds__(256) void k_psoftmax(const float* __restrict__ pscp,
                                                  unsigned short* __restrict__ pw) {
  const int row = blockIdx.x;          // b*64 + m
  const int b = row >> 6, m = row & 63;
  const int tid = threadIdx.x;
  float v[8];
  float mx = -1e30f;
#pragma unroll
  for (int i = 0; i < 8; i++) {
    int s = tid + i * 256;
    float acc = 0.f;
#pragma unroll
    for (int ks = 0; ks < 4; ks++)
      acc += pscp[((size_t)(ks * B_ + b) * M_ + m) * S_ + s];
    v[i] = acc;
    mx = fmaxf(mx, acc);
  }
#pragma unroll
  for (int off = 1; off < 64; off <<= 1) mx = fmaxf(mx, __shfl_xor(mx, off));
  __shared__ float rm[4], rs[4];
  if ((tid & 63) == 0) rm[tid >> 6] = mx;
  __syncthreads();
  mx = fmaxf(fmaxf(rm[0], rm[1]), fmaxf(rm[2], rm[3]));
  float sum = 0.f;
#pragma unroll
  for (int i = 0; i < 8; i++) {
    v[i] = exp2f(v[i] - mx);
    sum += v[i];
  }
#pragma unroll
  for (int off = 1; off < 64; off <<= 1) sum += __shfl_xor(sum, off);
  if ((tid & 63) == 0) rs[tid >> 6] = sum;
  __syncthreads();
  float inv = 1.f / (rs[0] + rs[1] + rs[2] + rs[3]);
#pragma unroll
  for (int i = 0; i < 8; i++)
    pw[(size_t)row * S_ + tid + i * 256] = bf16_of(v[i] * inv);
}

// ---------------- summary: split-K partials ----------------
__global__ __launch_bounds__(256) void k_summary_part(
    const unsigned short* __restrict__ pw, const unsigned short* __restrict__ tokTb,
    float* __restrict__ sump) {
  const int nt = blockIdx.x, ks = blockIdx.y, b = blockIdx.z;
  f32x4 acc[4];
  gemm_core(pw + (size_t)b * M_ * S_ + ks * 256,
            tokTb + (size_t)b * D_ * S_ + ks * 256, S_, 256, 0, nt * 64, acc);
  const int tid = threadIdx.x, w = tid >> 6, l = tid & 63;
  float* dst = sump + ((size_t)(ks * B_ + b) * M_) * D_;
#pragma unroll
  for (int n = 0; n < 4; n++) {
#pragma unroll
    for (int r = 0; r < 4; r++) {
      int m = w * 16 + (l >> 4) * 4 + r;
      int c = nt * 64 + n * 16 + (l & 15);
      dst[(size_t)m * D_ + c] = acc[n][r];
    }
  }
}

// combine summary partials -> comb[:, D_:]
__global__ void k_sumcomb(const float* __restrict__ sump,
                          unsigned short* __restrict__ comb) {
  int i = blockIdx.x * blockDim.x + threadIdx.x;
  if (i >= B_ * M_ * D_) return;
  int bm = i >> 10, c = i & 1023;
  int b = bm >> 6, m = bm & 63;
  float acc = 0.f;
#pragma unroll
  for (int ks = 0; ks < 8; ks++)
    acc += sump[((size_t)(ks * B_ + b) * M_ + m) * D_ + c];
  comb[((size_t)b * M_ + m) * (2 * D_) + D_ + c] = bf16_of(acc);
}

// ---------------- cell GEMM: split-K partials ----------------
__global__ __launch_bounds__(256) void k_cell_part(
    const unsigned short* __restrict__ comb, const unsigned short* __restrict__ cWb,
    float* __restrict__ cellp) {
  const int nt = blockIdx.x, mt = blockIdx.y, ks = blockIdx.z;
  f32x4 acc[4];
  gemm_core(comb + ks * 512, cWb + ks * 512, 2 * D_, 512, mt * 64, nt * 64, acc);
  const int tid = threadIdx.x, w = tid >> 6, l = tid & 63;
#pragma unroll
  for (int n = 0; n < 4; n++) {
#pragma unroll
    for (int r = 0; r < 4; r++) {
      int m = mt * 64 + w * 16 + (l >> 4) * 4 + r;
      int c = nt * 64 + n * 16 + (l & 15);
      cellp[((size_t)ks * (B_ * M_) + m) * (2 * D_) + c] = acc[n][r];
    }
  }
}

// ---------------- final gating (sums 4 cell partials + bias) ----------------
__global__ void k_newmem(const float* __restrict__ cellp,
                         const float* __restrict__ cb,
                         const float* __restrict__ memout,
                         float* __restrict__ out2) {
  int i = blockIdx.x * blockDim.x + threadIdx.x;
  if (i >= B_ * M_ * D_) return;
  int r = i >> 10, d = i & 1023;
  float gsum = cb[d], csum = cb[D_ + d];
#pragma unroll
  for (int ks = 0; ks < 4; ks++) {
    gsum += cellp[((size_t)ks * (B_ * M_) + r) * (2 * D_) + d];
    csum += cellp[((size_t)ks * (B_ * M_) + r) * (2 * D_) + D_ + d];
  }
  float sg = 1.f / (1.f + __expf(-gsum));
  float sc = 1.f / (1.f + __expf(-csum));
  out2[i] = memout[i] * sg + (1.f - sg) * (csum * sc);
}

// ---------------- launch ----------------
extern "C" void kernel_launch(void* const* d_in, const int* in_sizes, int n_in,
                              void* d_out, int out_size, void* d_ws, size_t ws_size,
                              hipStream_t stream) {
  const float* tokens = (const float*)d_in[0];
  const float* memory = (const float*)d_in[1];
  const float* Wq = (const float*)d_in[2];
  const float* bq = (const float*)d_in[3];
  const float* Wk = (const float*)d_in[4];
  const float* bk = (const float*)d_in[5];
  const float* Wv = (const float*)d_in[6];
  const float* bv = (const float*)d_in[7];
  const float* Wo = (const float*)d_in[8];
  const float* bo = (const float*)d_in[9];
  const float* pool_q = (const float*)d_in[10];
  const float* cell_W = (const float*)d_in[11];
  const float* cell_b = (const float*)d_in[12];

  size_t off = 0;
  auto alloc = [&](size_t bytes) -> void* {
    void* p = (char*)d_ws + off;
    off += (bytes + 255) & ~(size_t)255;
    return p;
  };
  unsigned short* xb    = (unsigned short*)alloc((size_t)BT_ * D_ * 2);
  unsigned short* Wqkvb = (unsigned short*)alloc((size_t)3 * D_ * D_ * 2);
  unsigned short* Wob   = (unsigned short*)alloc((size_t)D_ * D_ * 2);
  unsigned short* cWb   = (unsigned short*)alloc((size_t)(2 * D_) * (2 * D_) * 2);
  unsigned short* pqb   = (unsigned short*)alloc((size_t)M_ * D_ * 2);
  unsigned short* qg    = (unsigned short*)alloc((size_t)B_ * H_ * T_ * HD_ * 2);
  unsigned short* kg    = (unsigned short*)alloc((size_t)B_ * H_ * T_ * HD_ * 2);
  unsigned short* vTg   = (unsigned short*)alloc((size_t)B_ * H_ * HD_ * T_ * 2);
  unsigned short* ctxb  = (unsigned short*)alloc((size_t)BT_ * D_ * 2);
  unsigned short* tokb  = (unsigned short*)alloc((size_t)B_ * S_ * D_ * 2);
  unsigned short* tokTb = (unsigned short*)alloc((size_t)B_ * D_ * S_ * 2);
  float*          memout= (float*)alloc((size_t)B_ * M_ * D_ * 4);
  unsigned short* comb  = (unsigned short*)alloc((size_t)B_ * M_ * 2 * D_ * 2);
  unsigned short* pwt   = (unsigned short*)alloc((size_t)B_ * M_ * S_ * 2);
  float*          pscp  = (float*)alloc((size_t)4 * B_ * M_ * S_ * 4);
  float*          sump  = (float*)alloc((size_t)8 * B_ * M_ * D_ * 4);
  float*          cellp = (float*)alloc((size_t)4 * B_ * M_ * 2 * D_ * 4);

  float* out_tok = (float*)d_out;
  float* out_mem = out_tok + (size_t)B_ * S_ * D_;

  k_build_x<<<2048, 256, 0, stream>>>(tokens, memory, xb);
  k_cast_all<<<4096, 256, 0, stream>>>(Wq, Wk, Wv, Wo, cell_W, pool_q,
                                       Wqkvb, Wob, cWb, pqb);

  k_qkv<<<dim3(24, 33), 256, 0, stream>>>(xb, Wqkvb, bq, bk, bv, qg, kg, vTg);
  k_attn<<<1056, 256, 0, stream>>>(qg, kg, vTg, ctxb);
  k_out<<<dim3(8, 33), 256, 0, stream>>>(ctxb, Wob, bo, tokens, memory, out_tok,
                                         tokb, tokTb, memout, comb);
  k_pscore_part<<<dim3(32, 4, 2), 256, 0, stream>>>(pqb, tokb, pscp);
  k_psoftmax<<<B_ * M_, 256, 0, stream>>>(pscp, pwt);
  k_summary_part<<<dim3(16, 8, 2), 256, 0, stream>>>(pwt, tokTb, sump);
  k_sumcomb<<<512, 256, 0, stream>>>(sump, comb);
  k_cell_part<<<dim3(32, 2, 4), 256, 0, stream>>>(comb, cWb, cellp);
  k_newmem<<<512, 256, 0, stream>>>(cellp, cell_b, memout, out_mem);
}

// Round 8
// 218.448 us; speedup vs baseline: 1.5899x; 1.0046x over previous
//
#include <hip/hip_runtime.h>
#include <hip/hip_bf16.h>

#define B_  2
#define S_  2048
#define M_  64
#define D_  1024
#define T_  2112      // M_ + S_
#define H_  16
#define HD_ 64
#define BT_ (B_*T_)   // 4224
#define NEGBIG (-1e9f)
#define LOG2E 1.44269504f

typedef float f32x4  __attribute__((ext_vector_type(4)));
typedef short short8 __attribute__((ext_vector_type(8)));
typedef unsigned short u16x4 __attribute__((ext_vector_type(4)));
typedef __bf16 bf16x8 __attribute__((ext_vector_type(8)));

static __device__ __forceinline__ unsigned short bf16_of(float f) {
  __hip_bfloat16 h = __float2bfloat16(f);
  return __builtin_bit_cast(unsigned short, h);
}

static __device__ __forceinline__ f32x4 mfma_bf16(short8 a, short8 b, f32x4 c) {
  return __builtin_amdgcn_mfma_f32_16x16x32_bf16(
      __builtin_bit_cast(bf16x8, a), __builtin_bit_cast(bf16x8, b), c, 0, 0, 0);
}

// async global->LDS, 16B per lane; lds base must be wave-uniform (lane adds l*16).
static __device__ __forceinline__ void gload16(const void* g, void* lds) {
  __builtin_amdgcn_global_load_lds(
      (const __attribute__((address_space(1))) unsigned int*)g,
      (__attribute__((address_space(3))) unsigned int*)lds, 16, 0, 0);
}

// ---------------- cast / concat kernels ----------------

__global__ void k_build_x(const float* __restrict__ tokens,
                          const float* __restrict__ memory,
                          unsigned short* __restrict__ xb) {
  for (int i = blockIdx.x * blockDim.x + threadIdx.x; i < BT_ * D_;
       i += gridDim.x * blockDim.x) {
    int b = i / (T_ * D_);
    int rem = i - b * (T_ * D_);
    int t = rem / D_;
    int d = rem - t * D_;
    float v = (t < M_) ? memory[((size_t)b * M_ + t) * D_ + d]
                       : tokens[((size_t)b * S_ + (t - M_)) * D_ + d];
    xb[i] = bf16_of(v);
  }
}

// casts: Wq,Wk,Wv -> contiguous Wqkvb (3x1M), Wo (1M), cell_W (4M), pool_q (64K scaled)
__global__ void k_cast_all(const float* __restrict__ Wq, const float* __restrict__ Wk,
                           const float* __restrict__ Wv, const float* __restrict__ Wo,
                           const float* __restrict__ cW, const float* __restrict__ pq,
                           unsigned short* __restrict__ Wqkvb, unsigned short* __restrict__ Wob,
                           unsigned short* __restrict__ cWb, unsigned short* __restrict__ pqb) {
  const int NW = D_ * D_;            // 1M
  const int NC = 4 * D_ * D_;        // 4M
  const int NP = M_ * D_;            // 64K
  const int total = 4 * NW + NC + NP;
  for (int i = blockIdx.x * blockDim.x + threadIdx.x; i < total;
       i += gridDim.x * blockDim.x) {
    if (i < 3 * NW) {
      int which = i >> 20, j = i & (NW - 1);
      const float* s = (which == 0) ? Wq : (which == 1) ? Wk : Wv;
      Wqkvb[i] = bf16_of(s[j]);
    } else if (i < 4 * NW) {
      int j = i - 3 * NW;
      Wob[j] = bf16_of(Wo[j]);
    } else if (i < 4 * NW + NC) {
      int j = i - 4 * NW;
      cWb[j] = bf16_of(cW[j]);
    } else {
      int j = i - 4 * NW - NC;
      pqb[j] = bf16_of(pq[j] * 0.03125f * LOG2E);   // D^-0.5, exp2-domain
    }
  }
}

// ---------------- 128x128 GEMM core: dbuf BK=64, 1 barrier/K-tile, swizzled ----------------
// C[m][n] = sum_k A[m][k]*BT[n][k]; A,BT row-major stride K (K % 64 == 0).
// 256 threads = 4 waves; wave w owns 64x64 quadrant (wr=w>>1, wc=w&1), 4x4 frags.
// acc[i][j][r]: row = m0 + wr*64 + i*16 + (l>>4)*4 + r, col = n0 + wc*64 + j*16 + (l&15).
// LDS tiles [128][64] (128B rows = 8 x 16B units); both-sides XOR swizzle unit^=(row&7).
__device__ __forceinline__ void gemm128_core(const unsigned short* __restrict__ A,
                                             const unsigned short* __restrict__ BT,
                                             int K, int m0, int n0,
                                             f32x4 acc[4][4]) {
  __shared__ __align__(16) unsigned short As[2][128][64];
  __shared__ __align__(16) unsigned short Bs[2][128][64];
  const int tid = threadIdx.x;
  const int w = tid >> 6, l = tid & 63;
  const int wr = w >> 1, wc = w & 1;
  const int lr = l & 15, lg = l >> 4;
  f32x4 z; z[0] = z[1] = z[2] = z[3] = 0.f;
#pragma unroll
  for (int i = 0; i < 4; i++)
#pragma unroll
    for (int j = 0; j < 4; j++) acc[i][j] = z;

  // stage one BK=64 K-tile (A and B) into buffer buf; 8 gload16 issues/block.
  auto stage = [&](int buf, int k0) {
#pragma unroll
    for (int c = 0; c < 4; c++) {
      int rbase = c * 32 + w * 8;            // this wave's 8-row slab
      int rr = rbase + (l >> 3);             // lane's row
      int u = (l & 7) ^ (rr & 7);            // swizzled 16B-unit in source
      gload16(&A[(size_t)(m0 + rr) * K + k0 + u * 8], &As[buf][rbase][0]);
      gload16(&BT[(size_t)(n0 + rr) * K + k0 + u * 8], &Bs[buf][rbase][0]);
    }
  };

  stage(0, 0);
  __syncthreads();
  int cur = 0;
  const int NK = K >> 6;
  for (int kt = 0; kt < NK; kt++) {
    if (kt + 1 < NK) stage(cur ^ 1, (kt + 1) << 6);   // issue next tile early

    short8 a[4][2], b[4][2];
#pragma unroll
    for (int i = 0; i < 4; i++) {
      int row = wr * 64 + i * 16 + lr;
      int sw = row & 7;
#pragma unroll
      for (int kk = 0; kk < 2; kk++)
        a[i][kk] = *(const short8*)&As[cur][row][(((kk << 2) | lg) ^ sw) * 8];
    }
#pragma unroll
    for (int j = 0; j < 4; j++) {
      int row = wc * 64 + j * 16 + lr;
      int sw = row & 7;
#pragma unroll
      for (int kk = 0; kk < 2; kk++)
        b[j][kk] = *(const short8*)&Bs[cur][row][(((kk << 2) | lg) ^ sw) * 8];
    }
    __builtin_amdgcn_s_setprio(1);
#pragma unroll
    for (int kk = 0; kk < 2; kk++)
#pragma unroll
      for (int i = 0; i < 4; i++)
#pragma unroll
        for (int j = 0; j < 4; j++)
          acc[i][j] = mfma_bf16(a[i][kk], b[j][kk], acc[i][j]);
    __builtin_amdgcn_s_setprio(0);

    __syncthreads();   // drains this iter's prefetch + guards buffer swap
    cur ^= 1;
  }
}

// ---------------- small 64x64 GEMM core (partial-K capable) ----------------
__device__ __forceinline__ void gemm_core(const unsigned short* __restrict__ A,
                                          const unsigned short* __restrict__ BT,
                                          int ldk, int Klen, int m0, int n0,
                                          f32x4 acc[4]) {
  __shared__ __align__(16) unsigned short As[64][40];
  __shared__ __align__(16) unsigned short Bs[64][40];
  const int tid = threadIdx.x;
  const int w = tid >> 6, l = tid & 63;
  const int sr = tid >> 2, sc = (tid & 3) * 8;
  f32x4 z; z[0] = z[1] = z[2] = z[3] = 0.f;
  acc[0] = acc[1] = acc[2] = acc[3] = z;
  for (int k0 = 0; k0 < Klen; k0 += 32) {
    __syncthreads();
    *(short8*)&As[sr][sc] = *(const short8*)&A[(size_t)(m0 + sr) * ldk + k0 + sc];
    *(short8*)&Bs[sr][sc] = *(const short8*)&BT[(size_t)(n0 + sr) * ldk + k0 + sc];
    __syncthreads();
    short8 a = *(const short8*)&As[w * 16 + (l & 15)][(l >> 4) * 8];
#pragma unroll
    for (int n = 0; n < 4; n++) {
      short8 b = *(const short8*)&Bs[n * 16 + (l & 15)][(l >> 4) * 8];
      acc[n] = mfma_bf16(a, b, acc[n]);
    }
  }
}

// ---------------- fused QKV projection (128-tile, single launch) ----------------
// grid: x = n-tile (24: 8 per Q/K/V), y = m-tile (33). which = bx>>3.
__global__ __launch_bounds__(256) void k_qkv(
    const unsigned short* __restrict__ xb, const unsigned short* __restrict__ Wqkvb,
    const float* __restrict__ bq, const float* __restrict__ bk,
    const float* __restrict__ bv, unsigned short* __restrict__ qg,
    unsigned short* __restrict__ kg, unsigned short* __restrict__ vTg) {
  const int which = blockIdx.x >> 3;
  const unsigned short* W = Wqkvb + (size_t)which * D_ * D_;
  const float* bias = (which == 0) ? bq : ((which == 1) ? bk : bv);
  f32x4 acc[4][4];
  const int m0 = blockIdx.y * 128, n0 = (blockIdx.x & 7) * 128;
  gemm128_core(xb, W, D_, m0, n0, acc);
  const int tid = threadIdx.x, w = tid >> 6, l = tid & 63;
  const int wr = w >> 1, wc = w & 1;
#pragma unroll
  for (int i = 0; i < 4; i++) {
#pragma unroll
    for (int j = 0; j < 4; j++) {
#pragma unroll
      for (int r = 0; r < 4; r++) {
        int m = m0 + wr * 64 + i * 16 + (l >> 4) * 4 + r;
        int c = n0 + wc * 64 + j * 16 + (l & 15);
        int b = m / T_, t = m - b * T_;
        int h = c >> 6, dh = c & 63;
        int bh = b * H_ + h;
        float v = acc[i][j][r] + bias[c];
        if (which == 0)
          qg[((size_t)bh * T_ + t) * HD_ + dh] = bf16_of(v * 0.125f * LOG2E);
        else if (which == 1)
          kg[((size_t)bh * T_ + t) * HD_ + dh] = bf16_of(v);
        else
          vTg[((size_t)bh * HD_ + dh) * T_ + t] = bf16_of(v);
      }
    }
  }
}

// ---------------- fused attention: swapped-operand QK^T, lane-local softmax ----------------
// grid: 1056 blocks.  id = 8*((bh/8)*33 + qtr) + bh%8; qt = qtr==0 ? 0 : 33-qtr
// (bh-group -> XCD, heavy tiles first INCLUDING qt=0).
// Block = 4 waves, 64 q-rows; wave w owns rows [qt*64 + w*16, +16).
// QK^T computed as mfma(K, Q) -> lane owns one q-row (ql = lane&15): row max is
// in-register + 2 shfl; P packs to 4 ds_write_b64.  mrun/lrun are lane scalars.
__global__ __launch_bounds__(256) void k_attn(
    const unsigned short* __restrict__ qg, const unsigned short* __restrict__ kg,
    const unsigned short* __restrict__ vTg, unsigned short* __restrict__ ctx) {
  const int id = blockIdx.x;
  const int xcd = id & 7;
  const int rem = id >> 3;
  const int g = rem / 33, qtr = rem - g * 33;
  const int qt = (qtr == 0) ? 0 : 33 - qtr;
  const int bh = g * 8 + xcd;
  const int tid = threadIdx.x, w = tid >> 6, l = tid & 63;
  const int lr = l & 15, lg = l >> 4;
  __shared__ __align__(16) unsigned short Ks[2][64][64];
  __shared__ __align__(16) unsigned short Vs[2][64][64];
  __shared__ __align__(16) unsigned short Ps[4][16][72];

  const unsigned short* qb = qg + (size_t)bh * T_ * HD_;
  const unsigned short* kb = kg + (size_t)bh * T_ * HD_;
  const unsigned short* vb = vTg + (size_t)bh * HD_ * T_;

  // Q B-fragment: row = lr = this wave's q-row, cols lg*8
  short8 aq[2];
  const int qrow = qt * 64 + w * 16 + lr;
#pragma unroll
  for (int st = 0; st < 2; st++)
    aq[st] = *(const short8*)&qb[(size_t)qrow * HD_ + st * 32 + lg * 8];

  f32x4 zz; zz[0] = zz[1] = zz[2] = zz[3] = 0.f;
  f32x4 o[4];
  o[0] = o[1] = o[2] = o[3] = zz;
  float mrun = -1e30f, lrun = 0.f;   // lane-scalar state for q-row (w*16+lr)

  const int nkt = (qt == 0) ? 33 : qt + 1;

  // stage 64x64 K and V tiles (col kb2..+63) into buffer buf, swizzled source
  auto stage = [&](int buf, int kb2) {
#pragma unroll
    for (int i = 0; i < 2; i++) {
      int rr = w * 16 + i * 8 + (l >> 3);            // row within 64-tile
      int swz = ((l & 7) ^ (rr & 7)) * 8;            // swizzled 16B-unit (elems)
      gload16(&kb[(size_t)(kb2 + rr) * HD_ + swz], &Ks[buf][w * 16 + i * 8][0]);
      gload16(&vb[(size_t)rr * T_ + kb2 + swz], &Vs[buf][w * 16 + i * 8][0]);
    }
  };

  stage(0, 0);
  __syncthreads();
  int cur = 0;

  for (int j = 0; j < nkt; j++) {
    const int kbase = j * 64;
    if (j + 1 < nkt) stage(cur ^ 1, kbase + 64);     // async prefetch next tile

    // K A-fragments from LDS (swizzled read); row = k-local = n*16+lr
    short8 bkf[2][4];
#pragma unroll
    for (int n = 0; n < 4; n++) {
      int row = n * 16 + lr;
      int sw = lr & 7;
#pragma unroll
      for (int st = 0; st < 2; st++)
        bkf[st][n] = *(const short8*)&Ks[cur][row][((st * 4 + lg) ^ sw) * 8];
    }
    // S^T = K * Q^T : s[n][r] = S[k = kbase + n*16 + lg*4 + r][q-row ql=lr]
    f32x4 s[4];
    s[0] = s[1] = s[2] = s[3] = zz;
    __builtin_amdgcn_s_setprio(1);
#pragma unroll
    for (int st = 0; st < 2; st++)
#pragma unroll
      for (int n = 0; n < 4; n++)
        s[n] = mfma_bf16(bkf[st][n], aq[st], s[n]);
    __builtin_amdgcn_s_setprio(0);

    // causal mask on diagonal tile (qt==0 is all memory rows: no mask)
    if (qt > 0 && j == qt) {
      const int tql = w * 16 + lr;        // local q within 64
#pragma unroll
      for (int n = 0; n < 4; n++)
#pragma unroll
        for (int r = 0; r < 4; r++) {
          int tkl = n * 16 + lg * 4 + r;  // local k within 64
          if (tkl > tql) s[n][r] = NEGBIG;
        }
    }
    // row max: in-register over this lane's 16 values + 2 shfl across lg-groups
    float pm = s[0][0];
#pragma unroll
    for (int n = 0; n < 4; n++)
#pragma unroll
      for (int r = 0; r < 4; r++) pm = fmaxf(pm, s[n][r]);
    pm = fmaxf(pm, __shfl_xor(pm, 16));
    pm = fmaxf(pm, __shfl_xor(pm, 32));

    // defer-max: rescale only when some row's max grew by > 8 (exp2 domain)
    if (__any(pm > mrun + 8.f)) {
      float mn = fmaxf(mrun, pm);
      float fac = exp2f(mrun - mn);
      mrun = mn;
      lrun *= fac;
      float fr[4];
#pragma unroll
      for (int r = 0; r < 4; r++) fr[r] = __shfl(fac, lg * 4 + r);
#pragma unroll
      for (int n = 0; n < 4; n++)
#pragma unroll
        for (int r = 0; r < 4; r++) o[n][r] *= fr[r];
    }
    // P = exp2(S - m); lane-partial row sum; pack 4 k-values -> one b64 store
#pragma unroll
    for (int n = 0; n < 4; n++) {
      u16x4 pk;
#pragma unroll
      for (int r = 0; r < 4; r++) {
        float p = exp2f(s[n][r] - mrun);
        lrun += p;
        pk[r] = bf16_of(p);
      }
      *(u16x4*)&Ps[w][lr][n * 16 + lg * 4] = pk;
    }

    // V B-fragments from LDS (swizzled read), P A-fragments, then PV
    short8 bvf[2][4];
#pragma unroll
    for (int n = 0; n < 4; n++) {
      int row = n * 16 + lr;                          // dh
      int sw = lr & 7;
#pragma unroll
      for (int st = 0; st < 2; st++)
        bvf[st][n] = *(const short8*)&Vs[cur][row][((st * 4 + lg) ^ sw) * 8];
    }
    short8 ap[2];
#pragma unroll
    for (int st = 0; st < 2; st++)
      ap[st] = *(const short8*)&Ps[w][lr][st * 32 + lg * 8];
    __builtin_amdgcn_s_setprio(1);
#pragma unroll
    for (int st = 0; st < 2; st++)
#pragma unroll
      for (int n = 0; n < 4; n++)
        o[n] = mfma_bf16(ap[st], bvf[st][n], o[n]);
    __builtin_amdgcn_s_setprio(0);

    __syncthreads();   // drains prefetch (vmcnt) + guards buffer reuse
    cur ^= 1;
  }
  // epilogue: full row sum (reduce lane partials across lg-groups), then
  // redistribute to the o-accumulator's q-mapping (q = lg*4+r)
  lrun += __shfl_xor(lrun, 16);
  lrun += __shfl_xor(lrun, 32);
  float linv[4];
#pragma unroll
  for (int r = 0; r < 4; r++) linv[r] = 1.f / __shfl(lrun, lg * 4 + r);

  const int b = bh >> 4, h = bh & 15;
#pragma unroll
  for (int n = 0; n < 4; n++)
#pragma unroll
    for (int r = 0; r < 4; r++) {
      int tq = qt * 64 + w * 16 + lg * 4 + r;
      float val = o[n][r] * linv[r];
      ctx[((size_t)(b * T_ + tq)) * D_ + h * HD_ + n * 16 + lr] = bf16_of(val);
    }
}

// ---------------- output projection + residual + splits (128-tile) ----------------
__global__ __launch_bounds__(256) void k_out(
    const unsigned short* __restrict__ ctxb, const unsigned short* __restrict__ Wob,
    const float* __restrict__ bo, const float* __restrict__ tokens,
    const float* __restrict__ memory, float* __restrict__ out_tok,
    unsigned short* __restrict__ tokb, unsigned short* __restrict__ tokTb,
    float* __restrict__ memout, unsigned short* __restrict__ comb) {
  f32x4 acc[4][4];
  const int m0 = blockIdx.y * 128, n0 = blockIdx.x * 128;
  gemm128_core(ctxb, Wob, D_, m0, n0, acc);
  const int tid = threadIdx.x, w = tid >> 6, l = tid & 63;
  const int wr = w >> 1, wc = w & 1;
#pragma unroll
  for (int i = 0; i < 4; i++) {
#pragma unroll
    for (int j = 0; j < 4; j++) {
#pragma unroll
      for (int r = 0; r < 4; r++) {
        int m = m0 + wr * 64 + i * 16 + (l >> 4) * 4 + r;
        int c = n0 + wc * 64 + j * 16 + (l & 15);
        int b = m / T_, t = m - b * T_;
        float xo = (t < M_) ? memory[((size_t)b * M_ + t) * D_ + c]
                            : tokens[((size_t)b * S_ + (t - M_)) * D_ + c];
        float val = acc[i][j][r] + bo[c] + xo;
        if (t < M_) {
          memout[((size_t)b * M_ + t) * D_ + c] = val;
          comb[((size_t)b * M_ + t) * (2 * D_) + c] = bf16_of(val);
        } else {
          size_t ti = (size_t)b * S_ + (t - M_);
          out_tok[ti * D_ + c] = val;
          tokb[ti * D_ + c] = bf16_of(val);
          tokTb[((size_t)b * D_ + c) * S_ + (t - M_)] = bf16_of(val);
        }
      }
    }
  }
}

// ---------------- pool scores: split-K partials ----------------
__global__ __launch_bounds__(256) void k_pscore_part(
    const unsigned short* __restrict__ pqb, const unsigned short* __restrict__ tokb,
    float* __restrict__ pscp) {
  const int stile = blockIdx.x, ks = blockIdx.y, b = blockIdx.z;
  f32x4 acc[4];
  gemm_core(pqb + ks * 256, tokb + (size_t)b * S_ * D_ + ks * 256, D_, 256,
            0, stile * 64, acc);
  const int tid = threadIdx.x, w = tid >> 6, l = tid & 63;
  float* dst = pscp + ((size_t)(ks * B_ + b) * M_) * S_;
#pragma unroll
  for (int n = 0; n < 4; n++) {
#pragma unroll
    for (int r = 0; r < 4; r++) {
      int m = w * 16 + (l >> 4) * 4 + r;
      int s = stile * 64 + n * 16 + (l & 15);
      dst[(size_t)m * S_ + s] = acc[n][r];
    }
  }
}

// ---------------- pool softmax (sums 4 partials; exp2 domain) ----------------
__global__ __launch_bounds__(256) void k_psoftmax(const float* __restrict__ pscp,
                                                  unsigned short* __restrict__ pw) {
  const int row = blockIdx.x;          // b*64 + m
  const int b = row >> 6, m = row & 63;
  const int tid = threadIdx.x;
  float v[8];
  float mx = -1e30f;
#pragma unroll
  for (int i = 0; i < 8; i++) {
    int s = tid + i * 256;
    float acc = 0.f;
#pragma unroll
    for (int ks = 0; ks < 4; ks++)
      acc += pscp[((size_t)(ks * B_ + b) * M_ + m) * S_ + s];
    v[i] = acc;
    mx = fmaxf(mx, acc);
  }
#pragma unroll
  for (int off = 1; off < 64; off <<= 1) mx = fmaxf(mx, __shfl_xor(mx, off));
  __shared__ float rm[4], rs[4];
  if ((tid & 63) == 0) rm[tid >> 6] = mx;
  __syncthreads();
  mx = fmaxf(fmaxf(rm[0], rm[1]), fmaxf(rm[2], rm[3]));
  float sum = 0.f;
#pragma unroll
  for (int i = 0; i < 8; i++) {
    v[i] = exp2f(v[i] - mx);
    sum += v[i];
  }
#pragma unroll
  for (int off = 1; off < 64; off <<= 1) sum += __shfl_xor(sum, off);
  if ((tid & 63) == 0) rs[tid >> 6] = sum;
  __syncthreads();
  float inv = 1.f / (rs[0] + rs[1] + rs[2] + rs[3]);
#pragma unroll
  for (int i = 0; i < 8; i++)
    pw[(size_t)row * S_ + tid + i * 256] = bf16_of(v[i] * inv);
}

// ---------------- summary: split-K partials ----------------
__global__ __launch_bounds__(256) void k_summary_part(
    const unsigned short* __restrict__ pw, const unsigned short* __restrict__ tokTb,
    float* __restrict__ sump) {
  const int nt = blockIdx.x, ks = blockIdx.y, b = blockIdx.z;
  f32x4 acc[4];
  gemm_core(pw + (size_t)b * M_ * S_ + ks * 256,
            tokTb + (size_t)b * D_ * S_ + ks * 256, S_, 256, 0, nt * 64, acc);
  const int tid = threadIdx.x, w = tid >> 6, l = tid & 63;
  float* dst = sump + ((size_t)(ks * B_ + b) * M_) * D_;
#pragma unroll
  for (int n = 0; n < 4; n++) {
#pragma unroll
    for (int r = 0; r < 4; r++) {
      int m = w * 16 + (l >> 4) * 4 + r;
      int c = nt * 64 + n * 16 + (l & 15);
      dst[(size_t)m * D_ + c] = acc[n][r];
    }
  }
}

// combine summary partials -> comb[:, D_:]
__global__ void k_sumcomb(const float* __restrict__ sump,
                          unsigned short* __restrict__ comb) {
  int i = blockIdx.x * blockDim.x + threadIdx.x;
  if (i >= B_ * M_ * D_) return;
  int bm = i >> 10, c = i & 1023;
  int b = bm >> 6, m = bm & 63;
  float acc = 0.f;
#pragma unroll
  for (int ks = 0; ks < 8; ks++)
    acc += sump[((size_t)(ks * B_ + b) * M_ + m) * D_ + c];
  comb[((size_t)b * M_ + m) * (2 * D_) + D_ + c] = bf16_of(acc);
}

// ---------------- cell GEMM: split-K partials ----------------
__global__ __launch_bounds__(256) void k_cell_part(
    const unsigned short* __restrict__ comb, const unsigned short* __restrict__ cWb,
    float* __restrict__ cellp) {
  const int nt = blockIdx.x, mt = blockIdx.y, ks = blockIdx.z;
  f32x4 acc[4];
  gemm_core(comb + ks * 512, cWb + ks * 512, 2 * D_, 512, mt * 64, nt * 64, acc);
  const int tid = threadIdx.x, w = tid >> 6, l = tid & 63;
#pragma unroll
  for (int n = 0; n < 4; n++) {
#pragma unroll
    for (int r = 0; r < 4; r++) {
      int m = mt * 64 + w * 16 + (l >> 4) * 4 + r;
      int c = nt * 64 + n * 16 + (l & 15);
      cellp[((size_t)ks * (B_ * M_) + m) * (2 * D_) + c] = acc[n][r];
    }
  }
}

// ---------------- final gating (sums 4 cell partials + bias) ----------------
__global__ void k_newmem(const float* __restrict__ cellp,
                         const float* __restrict__ cb,
                         const float* __restrict__ memout,
                         float* __restrict__ out2) {
  int i = blockIdx.x * blockDim.x + threadIdx.x;
  if (i >= B_ * M_ * D_) return;
  int r = i >> 10, d = i & 1023;
  float gsum = cb[d], csum = cb[D_ + d];
#pragma unroll
  for (int ks = 0; ks < 4; ks++) {
    gsum += cellp[((size_t)ks * (B_ * M_) + r) * (2 * D_) + d];
    csum += cellp[((size_t)ks * (B_ * M_) + r) * (2 * D_) + D_ + d];
  }
  float sg = 1.f / (1.f + __expf(-gsum));
  float sc = 1.f / (1.f + __expf(-csum));
  out2[i] = memout[i] * sg + (1.f - sg) * (csum * sc);
}

// ---------------- launch ----------------
extern "C" void kernel_launch(void* const* d_in, const int* in_sizes, int n_in,
                              void* d_out, int out_size, void* d_ws, size_t ws_size,
                              hipStream_t stream) {
  const float* tokens = (const float*)d_in[0];
  const float* memory = (const float*)d_in[1];
  const float* Wq = (const float*)d_in[2];
  const float* bq = (const float*)d_in[3];
  const float* Wk = (const float*)d_in[4];
  const float* bk = (const float*)d_in[5];
  const float* Wv = (const float*)d_in[6];
  const float* bv = (const float*)d_in[7];
  const float* Wo = (const float*)d_in[8];
  const float* bo = (const float*)d_in[9];
  const float* pool_q = (const float*)d_in[10];
  const float* cell_W = (const float*)d_in[11];
  const float* cell_b = (const float*)d_in[12];

  size_t off = 0;
  auto alloc = [&](size_t bytes) -> void* {
    void* p = (char*)d_ws + off;
    off += (bytes + 255) & ~(size_t)255;
    return p;
  };
  unsigned short* xb    = (unsigned short*)alloc((size_t)BT_ * D_ * 2);
  unsigned short* Wqkvb = (unsigned short*)alloc((size_t)3 * D_ * D_ * 2);
  unsigned short* Wob   = (unsigned short*)alloc((size_t)D_ * D_ * 2);
  unsigned short* cWb   = (unsigned short*)alloc((size_t)(2 * D_) * (2 * D_) * 2);
  unsigned short* pqb   = (unsigned short*)alloc((size_t)M_ * D_ * 2);
  unsigned short* qg    = (unsigned short*)alloc((size_t)B_ * H_ * T_ * HD_ * 2);
  unsigned short* kg    = (unsigned short*)alloc((size_t)B_ * H_ * T_ * HD_ * 2);
  unsigned short* vTg   = (unsigned short*)alloc((size_t)B_ * H_ * HD_ * T_ * 2);
  unsigned short* ctxb  = (unsigned short*)alloc((size_t)BT_ * D_ * 2);
  unsigned short* tokb  = (unsigned short*)alloc((size_t)B_ * S_ * D_ * 2);
  unsigned short* tokTb = (unsigned short*)alloc((size_t)B_ * D_ * S_ * 2);
  float*          memout= (float*)alloc((size_t)B_ * M_ * D_ * 4);
  unsigned short* comb  = (unsigned short*)alloc((size_t)B_ * M_ * 2 * D_ * 2);
  unsigned short* pwt   = (unsigned short*)alloc((size_t)B_ * M_ * S_ * 2);
  float*          pscp  = (float*)alloc((size_t)4 * B_ * M_ * S_ * 4);
  float*          sump  = (float*)alloc((size_t)8 * B_ * M_ * D_ * 4);
  float*          cellp = (float*)alloc((size_t)4 * B_ * M_ * 2 * D_ * 4);

  float* out_tok = (float*)d_out;
  float* out_mem = out_tok + (size_t)B_ * S_ * D_;

  k_build_x<<<2048, 256, 0, stream>>>(tokens, memory, xb);
  k_cast_all<<<4096, 256, 0, stream>>>(Wq, Wk, Wv, Wo, cell_W, pool_q,
                                       Wqkvb, Wob, cWb, pqb);

  k_qkv<<<dim3(24, 33), 256, 0, stream>>>(xb, Wqkvb, bq, bk, bv, qg, kg, vTg);
  k_attn<<<1056, 256, 0, stream>>>(qg, kg, vTg, ctxb);
  k_out<<<dim3(8, 33), 256, 0, stream>>>(ctxb, Wob, bo, tokens, memory, out_tok,
                                         tokb, tokTb, memout, comb);
  k_pscore_part<<<dim3(32, 4, 2), 256, 0, stream>>>(pqb, tokb, pscp);
  k_psoftmax<<<B_ * M_, 256, 0, stream>>>(pscp, pwt);
  k_summary_part<<<dim3(16, 8, 2), 256, 0, stream>>>(pwt, tokTb, sump);
  k_sumcomb<<<512, 256, 0, stream>>>(sump, comb);
  k_cell_part<<<dim3(32, 2, 4), 256, 0, stream>>>(comb, cWb, cellp);
  k_newmem<<<512, 256, 0, stream>>>(cellp, cell_b, memout, out_mem);
}